// Round 1
// baseline (1072.689 us; speedup 1.0000x reference)
//
#include <hip/hip_runtime.h>

namespace {

constexpr int kNQ   = 10000;
constexpr int kCams = 6;
constexpr int kC    = 256;
constexpr int kH    = 8;
constexpr int kDh   = 32;
constexpr int kNK   = 13600;
constexpr float kEps = 1e-5f;

// ---------------------------------------------------------------------------
// Generic fp32 GEMM: out[M x N] = (A [+ A2]) @ W[K=256 x N] + bias [+ addend]
// A rows are contiguous with stride K=256. Block = N threads, 32 rows/block.
// In-place safe (out == A): rows are fully staged to LDS before any write.
// ---------------------------------------------------------------------------
template <int N>
__global__ __launch_bounds__(N) void k_gemm(const float* __restrict__ A,
                                            const float* __restrict__ A2,
                                            const float* __restrict__ W,
                                            const float* __restrict__ bias,
                                            const float* __restrict__ addend,
                                            float* __restrict__ out, int M) {
  constexpr int K = 256;
  constexpr int TM = 32;
  __shared__ float As[TM * K];
  const int tid = threadIdx.x;
  const int row0 = blockIdx.x * TM;
  const int rows = (M - row0 < TM) ? (M - row0) : TM;
  const int lim = rows * K;
  const long long base = (long long)row0 * K;
  for (int i = tid; i < TM * K; i += N) {
    float v = 0.f;
    if (i < lim) {
      v = A[base + i];
      if (A2) v += A2[base + i];
    }
    As[i] = v;
  }
  __syncthreads();

  float acc[TM];
#pragma unroll
  for (int r = 0; r < TM; ++r) acc[r] = 0.f;

  const int n = tid;
  for (int k = 0; k < K; k += 4) {
    const float w0 = W[(k + 0) * N + n];
    const float w1 = W[(k + 1) * N + n];
    const float w2 = W[(k + 2) * N + n];
    const float w3 = W[(k + 3) * N + n];
#pragma unroll
    for (int r = 0; r < TM; ++r) {
      const float4 a = *reinterpret_cast<const float4*>(&As[r * K + k]);
      float t = acc[r];
      t = fmaf(a.x, w0, t);
      t = fmaf(a.y, w1, t);
      t = fmaf(a.z, w2, t);
      t = fmaf(a.w, w3, t);
      acc[r] = t;
    }
  }

  const float b = bias ? bias[n] : 0.f;
  for (int r = 0; r < TM; ++r) {
    const int row = row0 + r;
    if (row < M) {
      float v = acc[r] + b;
      if (addend) v += addend[(long long)row * N + n];
      out[(long long)row * N + n] = v;
    }
  }
}

// ---------------------------------------------------------------------------
// Value projection GEMM: vproj[cam][h][n][d] = value[n][cam][:] @ W_val[:, h*32+d] + b
// grid = (kNK/32, kCams), block = 256
// ---------------------------------------------------------------------------
__global__ __launch_bounds__(256) void k_gemm_vproj(const float* __restrict__ value,
                                                    const float* __restrict__ W,
                                                    const float* __restrict__ bias,
                                                    float* __restrict__ out) {
  constexpr int K = 256;
  constexpr int TM = 32;
  constexpr int N = 256;
  __shared__ float As[TM * K];
  const int tid = threadIdx.x;
  const int cam = blockIdx.y;
  const int row0 = blockIdx.x * TM;
  for (int i = tid; i < TM * K; i += N) {
    const int r = i >> 8;
    const int k = i & 255;
    const int nrow = row0 + r;
    As[i] = value[((long long)nrow * kCams + cam) * K + k];
  }
  __syncthreads();

  float acc[TM];
#pragma unroll
  for (int r = 0; r < TM; ++r) acc[r] = 0.f;

  const int n = tid;
  for (int k = 0; k < K; k += 4) {
    const float w0 = W[(k + 0) * N + n];
    const float w1 = W[(k + 1) * N + n];
    const float w2 = W[(k + 2) * N + n];
    const float w3 = W[(k + 3) * N + n];
#pragma unroll
    for (int r = 0; r < TM; ++r) {
      const float4 a = *reinterpret_cast<const float4*>(&As[r * K + k]);
      float t = acc[r];
      t = fmaf(a.x, w0, t);
      t = fmaf(a.y, w1, t);
      t = fmaf(a.z, w2, t);
      t = fmaf(a.w, w3, t);
      acc[r] = t;
    }
  }

  const int h = tid >> 5;
  const int d = tid & 31;
  const float b = bias[tid];
  const long long obase = (((long long)cam * kH + h) * kNK) * kDh + d;
  for (int r = 0; r < TM; ++r) {
    out[obase + (long long)(row0 + r) * kDh] = acc[r] + b;
  }
}

// ---------------------------------------------------------------------------
// Softmax over each 16-wide group (per head), 128 logits per query.
// ---------------------------------------------------------------------------
__global__ __launch_bounds__(128) void k_softmax16(float* __restrict__ aw) {
  const int nq = blockIdx.x;
  const int t = threadIdx.x;
  float v = aw[(long long)nq * 128 + t];
  float mx = v;
#pragma unroll
  for (int s = 1; s < 16; s <<= 1) mx = fmaxf(mx, __shfl_xor(mx, s));
  const float e = expf(v - mx);
  float sm = e;
#pragma unroll
  for (int s = 1; s < 16; s <<= 1) sm += __shfl_xor(sm, s);
  aw[(long long)nq * 128 + t] = e / sm;
}

// ---------------------------------------------------------------------------
// Camera projection of reference points + visibility mask.
// thread = (cam, nq)
// ---------------------------------------------------------------------------
__global__ __launch_bounds__(256) void k_proj_ref(const float* __restrict__ refpts,
                                                  const float* __restrict__ l2i,
                                                  const float* __restrict__ img_shape,
                                                  float* __restrict__ refcam,
                                                  float* __restrict__ valid) {
  const int idx = blockIdx.x * blockDim.x + threadIdx.x;
  if (idx >= kCams * kNQ) return;
  const int cam = idx / kNQ;
  const int nq = idx - cam * kNQ;
  const float* Mp = l2i + cam * 12;
  float m[12];
#pragma unroll
  for (int i = 0; i < 12; ++i) m[i] = Mp[i];
  const float ih = img_shape[cam * 2 + 0];
  const float iw = img_shape[cam * 2 + 1];
  float anyv = 0.f;
  float* rcout = refcam + (long long)idx * 8;
#pragma unroll
  for (int r = 0; r < 4; ++r) {
    const float* rp = refpts + ((long long)nq * 4 + r) * 3;
    const float X = rp[0] * 102.4f + (-51.2f);
    const float Y = rp[1] * 102.4f + (-51.2f);
    const float Z = rp[2] * 8.0f + (-5.0f);
    const float cx = m[0] * X + m[1] * Y + m[2] * Z + m[3];
    const float cy = m[4] * X + m[5] * Y + m[6] * Z + m[7];
    const float cz = m[8] * X + m[9] * Y + m[10] * Z + m[11];
    const float zc = fmaxf(cz, kEps);
    const float xn = cx / zc / iw;
    const float yn = cy / zc / ih;
    rcout[r * 2 + 0] = xn;
    rcout[r * 2 + 1] = yn;
    if ((cz > kEps) && (xn > 0.f) && (xn < 1.f) && (yn > 0.f) && (yn < 1.f)) anyv = 1.f;
  }
  valid[idx] = anyv;
}

// ---------------------------------------------------------------------------
// Bilinear sampling + attention-weighted accumulation.
// block = (nq, cam), 256 threads: tid = h*32 + d
// acc[cam][nq][h*32+d] = sum_{l,r} aw * bilinear(vproj[cam][h][level l], loc)
// ---------------------------------------------------------------------------
__global__ __launch_bounds__(256) void k_sample(const float* __restrict__ vproj,
                                                const float* __restrict__ refcam,
                                                const float* __restrict__ off,
                                                const float* __restrict__ aw,
                                                float* __restrict__ acc) {
  const int nq = blockIdx.x;
  const int cam = blockIdx.y;
  const int tid = threadIdx.x;
  const int h = tid >> 5;
  const int d = tid & 31;
  static constexpr int SHH[4] = {64, 32, 16, 8};
  static constexpr int SHW[4] = {160, 80, 40, 20};
  static constexpr int LSI[4] = {0, 10240, 12800, 13440};

  const float* rc = refcam + (long long)(cam * kNQ + nq) * 8;
  const float* offp = off + (long long)nq * 256 + h * 32;
  const float* awp = aw + (long long)nq * 128 + h * 16;

  float s = 0.f;
#pragma unroll
  for (int l = 0; l < 4; ++l) {
    const int Hl = SHH[l];
    const int Wl = SHW[l];
    const float Hf = (float)Hl;
    const float Wf = (float)Wl;
    const float* vf = vproj + (((long long)cam * kH + h) * kNK + LSI[l]) * kDh + d;
#pragma unroll
    for (int r = 0; r < 4; ++r) {
      const float w = awp[l * 4 + r];
      const float locx = rc[r * 2 + 0] + offp[l * 8 + r * 2 + 0] / Wf;
      const float locy = rc[r * 2 + 1] + offp[l * 8 + r * 2 + 1] / Hf;
      const float x = locx * Wf - 0.5f;
      const float y = locy * Hf - 0.5f;
      const float x0 = floorf(x);
      const float y0 = floorf(y);
      const float lx = x - x0;
      const float ly = y - y0;
      const int ix = (int)x0;
      const int iy = (int)y0;
      const bool xin0 = (ix >= 0) && (ix < Wl);
      const bool xin1 = (ix + 1 >= 0) && (ix + 1 < Wl);
      const bool yin0 = (iy >= 0) && (iy < Hl);
      const bool yin1 = (iy + 1 >= 0) && (iy + 1 < Hl);
      float v00 = 0.f, v01 = 0.f, v10 = 0.f, v11 = 0.f;
      if (yin0 && xin0) v00 = vf[(iy * Wl + ix) * kDh];
      if (yin0 && xin1) v01 = vf[(iy * Wl + ix + 1) * kDh];
      if (yin1 && xin0) v10 = vf[((iy + 1) * Wl + ix) * kDh];
      if (yin1 && xin1) v11 = vf[((iy + 1) * Wl + ix + 1) * kDh];
      s += w * ((1.f - ly) * ((1.f - lx) * v00 + lx * v01) +
                ly * ((1.f - lx) * v10 + lx * v11));
    }
  }
  acc[((long long)cam * kNQ + nq) * kC + tid] = s;
}

// ---------------------------------------------------------------------------
// Masked mean over cameras: slots[nq][c] = sum_cam acc*valid / max(count,1)
// ---------------------------------------------------------------------------
__global__ __launch_bounds__(256) void k_combine(const float* __restrict__ acc,
                                                 const float* __restrict__ valid,
                                                 float* __restrict__ slots) {
  const int nq = blockIdx.x;
  const int c = threadIdx.x;
  float cnt = 0.f;
  float s = 0.f;
#pragma unroll
  for (int cam = 0; cam < kCams; ++cam) {
    const float v = valid[cam * kNQ + nq];
    cnt += v;
    s += acc[((long long)cam * kNQ + nq) * kC + c] * v;
  }
  slots[(long long)nq * kC + c] = s / fmaxf(cnt, 1.f);
}

}  // namespace

extern "C" void kernel_launch(void* const* d_in, const int* in_sizes, int n_in,
                              void* d_out, int out_size, void* d_ws, size_t ws_size,
                              hipStream_t stream) {
  (void)in_sizes; (void)n_in; (void)out_size; (void)ws_size;
  const float* query     = (const float*)d_in[0];
  const float* query_pos = (const float*)d_in[1];
  const float* value     = (const float*)d_in[2];
  const float* refpts    = (const float*)d_in[3];
  const float* l2i       = (const float*)d_in[4];
  const float* img_shape = (const float*)d_in[5];
  // d_in[6] spatial_shapes, d_in[7] level_start_index: compile-time constants
  const float* W_val  = (const float*)d_in[8];
  const float* b_val  = (const float*)d_in[9];
  const float* W_samp = (const float*)d_in[10];
  const float* b_samp = (const float*)d_in[11];
  const float* W_attn = (const float*)d_in[12];
  const float* b_attn = (const float*)d_in[13];
  const float* W_dout = (const float*)d_in[14];
  const float* b_dout = (const float*)d_in[15];
  const float* W_out  = (const float*)d_in[16];
  const float* b_out  = (const float*)d_in[17];

  float* ws = (float*)d_ws;
  float* off    = ws;                      // 2,560,000 floats
  float* aw     = off + 2560000;           // 1,280,000
  float* refcam = aw + 1280000;            //   480,000
  float* valid  = refcam + 480000;         //    60,000
  float* vproj  = valid + 60000;           // 20,889,600
  float* acc    = vproj + 20889600;        // 15,360,000
  float* slots  = vproj;                   // alias: vproj dead after k_sample
  float* out    = (float*)d_out;

  // q-projections (q+qpos fused into staging)
  k_gemm<256><<<dim3((kNQ + 31) / 32), 256, 0, stream>>>(query, query_pos, W_samp,
                                                         b_samp, nullptr, off, kNQ);
  k_gemm<128><<<dim3((kNQ + 31) / 32), 128, 0, stream>>>(query, query_pos, W_attn,
                                                         b_attn, nullptr, aw, kNQ);
  k_softmax16<<<dim3(kNQ), 128, 0, stream>>>(aw);

  // camera projection + visibility
  k_proj_ref<<<dim3((kCams * kNQ + 255) / 256), 256, 0, stream>>>(refpts, l2i,
                                                                  img_shape, refcam,
                                                                  valid);
  // value projection
  k_gemm_vproj<<<dim3(kNK / 32, kCams), 256, 0, stream>>>(value, W_val, b_val, vproj);

  // bilinear sampling + weighted accumulation
  k_sample<<<dim3(kNQ, kCams), 256, 0, stream>>>(vproj, refcam, off, aw, acc);

  // per-camera output projection (in-place on acc)
  k_gemm<256><<<dim3((kCams * kNQ + 31) / 32), 256, 0, stream>>>(acc, nullptr, W_dout,
                                                                 b_dout, nullptr, acc,
                                                                 kCams * kNQ);
  // masked mean over cameras
  k_combine<<<dim3(kNQ), 256, 0, stream>>>(acc, valid, slots);

  // final projection + residual
  k_gemm<256><<<dim3((kNQ + 31) / 32), 256, 0, stream>>>(slots, nullptr, W_out, b_out,
                                                         query, out, kNQ);
}

// Round 2
// 640.538 us; speedup vs baseline: 1.6747x; 1.6747x over previous
//
#include <hip/hip_runtime.h>

namespace {

constexpr int kNQ   = 10000;
constexpr int kCams = 6;
constexpr int kC    = 256;
constexpr int kH    = 8;
constexpr int kDh   = 32;
constexpr int kNK   = 13600;
constexpr float kEps = 1e-5f;

// ---------------------------------------------------------------------------
// fp32 GEMM, 2 cols/thread: out[M x N] = (A [+A2]) @ W[256 x N] + bias [+addend]
// Block = N/2 threads, 32 rows/block. In-place safe (rows staged before write).
// ---------------------------------------------------------------------------
template <int N>
__global__ __launch_bounds__(N / 2) void k_gemm2(const float* __restrict__ A,
                                                 const float* __restrict__ A2,
                                                 const float* __restrict__ W,
                                                 const float* __restrict__ bias,
                                                 const float* __restrict__ addend,
                                                 float* __restrict__ out, int M) {
  constexpr int K = 256;
  constexpr int TM = 32;
  constexpr int T = N / 2;
  __shared__ float As[TM * K];
  const int tid = threadIdx.x;
  const int row0 = blockIdx.x * TM;
  const int rows = (M - row0 < TM) ? (M - row0) : TM;
  const int lim = rows * K;
  const long long base = (long long)row0 * K;
  for (int i = tid * 4; i < TM * K; i += T * 4) {
    float4 v = {0.f, 0.f, 0.f, 0.f};
    if (i < lim) {
      v = *reinterpret_cast<const float4*>(A + base + i);
      if (A2) {
        const float4 u = *reinterpret_cast<const float4*>(A2 + base + i);
        v.x += u.x; v.y += u.y; v.z += u.z; v.w += u.w;
      }
    }
    *reinterpret_cast<float4*>(&As[i]) = v;
  }
  __syncthreads();

  float acc0[TM], acc1[TM];
#pragma unroll
  for (int r = 0; r < TM; ++r) { acc0[r] = 0.f; acc1[r] = 0.f; }

  const int c0 = tid;
  const int c1 = tid + T;
  for (int k = 0; k < K; k += 4) {
    const float wa0 = W[(k + 0) * N + c0], wb0 = W[(k + 0) * N + c1];
    const float wa1 = W[(k + 1) * N + c0], wb1 = W[(k + 1) * N + c1];
    const float wa2 = W[(k + 2) * N + c0], wb2 = W[(k + 2) * N + c1];
    const float wa3 = W[(k + 3) * N + c0], wb3 = W[(k + 3) * N + c1];
#pragma unroll
    for (int r = 0; r < TM; ++r) {
      const float4 a = *reinterpret_cast<const float4*>(&As[r * K + k]);
      acc0[r] = fmaf(a.w, wa3, fmaf(a.z, wa2, fmaf(a.y, wa1, fmaf(a.x, wa0, acc0[r]))));
      acc1[r] = fmaf(a.w, wb3, fmaf(a.z, wb2, fmaf(a.y, wb1, fmaf(a.x, wb0, acc1[r]))));
    }
  }

  const float b0 = bias ? bias[c0] : 0.f;
  const float b1 = bias ? bias[c1] : 0.f;
  for (int r = 0; r < TM; ++r) {
    const int row = row0 + r;
    if (row < M) {
      float v0 = acc0[r] + b0;
      float v1 = acc1[r] + b1;
      if (addend) {
        v0 += addend[(long long)row * N + c0];
        v1 += addend[(long long)row * N + c1];
      }
      out[(long long)row * N + c0] = v0;
      out[(long long)row * N + c1] = v1;
    }
  }
}

// ---------------------------------------------------------------------------
// Value projection: vproj[cam][h][n][d] = value[n][cam][:] @ W_val + b_val
// grid = (kNK/32, kCams), block = 128, 2 cols/thread
// ---------------------------------------------------------------------------
__global__ __launch_bounds__(128) void k_gemm_vproj(const float* __restrict__ value,
                                                    const float* __restrict__ W,
                                                    const float* __restrict__ bias,
                                                    float* __restrict__ out) {
  constexpr int K = 256;
  constexpr int TM = 32;
  constexpr int N = 256;
  constexpr int T = 128;
  __shared__ float As[TM * K];
  const int tid = threadIdx.x;
  const int cam = blockIdx.y;
  const int row0 = blockIdx.x * TM;
  for (int i = tid * 4; i < TM * K; i += T * 4) {
    const int r = i >> 8;
    const int k = i & 255;
    *reinterpret_cast<float4*>(&As[i]) = *reinterpret_cast<const float4*>(
        value + ((long long)(row0 + r) * kCams + cam) * K + k);
  }
  __syncthreads();

  float acc0[TM], acc1[TM];
#pragma unroll
  for (int r = 0; r < TM; ++r) { acc0[r] = 0.f; acc1[r] = 0.f; }

  const int c0 = tid;
  const int c1 = tid + T;
  for (int k = 0; k < K; k += 4) {
    const float wa0 = W[(k + 0) * N + c0], wb0 = W[(k + 0) * N + c1];
    const float wa1 = W[(k + 1) * N + c0], wb1 = W[(k + 1) * N + c1];
    const float wa2 = W[(k + 2) * N + c0], wb2 = W[(k + 2) * N + c1];
    const float wa3 = W[(k + 3) * N + c0], wb3 = W[(k + 3) * N + c1];
#pragma unroll
    for (int r = 0; r < TM; ++r) {
      const float4 a = *reinterpret_cast<const float4*>(&As[r * K + k]);
      acc0[r] = fmaf(a.w, wa3, fmaf(a.z, wa2, fmaf(a.y, wa1, fmaf(a.x, wa0, acc0[r]))));
      acc1[r] = fmaf(a.w, wb3, fmaf(a.z, wb2, fmaf(a.y, wb1, fmaf(a.x, wb0, acc1[r]))));
    }
  }

  const float b0 = bias[c0];
  const float b1 = bias[c1];
  const int h0 = c0 >> 5, d0 = c0 & 31;
  const int h1 = c1 >> 5, d1 = c1 & 31;
  const long long ob0 = ((long long)(cam * kH + h0) * kNK) * kDh + d0;
  const long long ob1 = ((long long)(cam * kH + h1) * kNK) * kDh + d1;
  for (int r = 0; r < TM; ++r) {
    out[ob0 + (long long)(row0 + r) * kDh] = acc0[r] + b0;
    out[ob1 + (long long)(row0 + r) * kDh] = acc1[r] + b1;
  }
}

// ---------------------------------------------------------------------------
// Softmax over each 16-wide group (per head), 128 logits per query.
// ---------------------------------------------------------------------------
__global__ __launch_bounds__(128) void k_softmax16(float* __restrict__ aw) {
  const int nq = blockIdx.x;
  const int t = threadIdx.x;
  float v = aw[(long long)nq * 128 + t];
  float mx = v;
#pragma unroll
  for (int s = 1; s < 16; s <<= 1) mx = fmaxf(mx, __shfl_xor(mx, s));
  const float e = expf(v - mx);
  float sm = e;
#pragma unroll
  for (int s = 1; s < 16; s <<= 1) sm += __shfl_xor(sm, s);
  aw[(long long)nq * 128 + t] = e / sm;
}

// ---------------------------------------------------------------------------
// Camera projection of reference points + visibility mask.
// ---------------------------------------------------------------------------
__global__ __launch_bounds__(256) void k_proj_ref(const float* __restrict__ refpts,
                                                  const float* __restrict__ l2i,
                                                  const float* __restrict__ img_shape,
                                                  float* __restrict__ refcam,
                                                  float* __restrict__ valid) {
  const int idx = blockIdx.x * blockDim.x + threadIdx.x;
  if (idx >= kCams * kNQ) return;
  const int cam = idx / kNQ;
  const int nq = idx - cam * kNQ;
  const float* Mp = l2i + cam * 12;
  float m[12];
#pragma unroll
  for (int i = 0; i < 12; ++i) m[i] = Mp[i];
  const float ih = img_shape[cam * 2 + 0];
  const float iw = img_shape[cam * 2 + 1];
  float anyv = 0.f;
  float* rcout = refcam + (long long)idx * 8;
#pragma unroll
  for (int r = 0; r < 4; ++r) {
    const float* rp = refpts + ((long long)nq * 4 + r) * 3;
    const float X = rp[0] * 102.4f + (-51.2f);
    const float Y = rp[1] * 102.4f + (-51.2f);
    const float Z = rp[2] * 8.0f + (-5.0f);
    const float cx = m[0] * X + m[1] * Y + m[2] * Z + m[3];
    const float cy = m[4] * X + m[5] * Y + m[6] * Z + m[7];
    const float cz = m[8] * X + m[9] * Y + m[10] * Z + m[11];
    const float zc = fmaxf(cz, kEps);
    const float xn = cx / zc / iw;
    const float yn = cy / zc / ih;
    rcout[r * 2 + 0] = xn;
    rcout[r * 2 + 1] = yn;
    if ((cz > kEps) && (xn > 0.f) && (xn < 1.f) && (yn > 0.f) && (yn < 1.f)) anyv = 1.f;
  }
  valid[idx] = anyv;
}

// ---------------------------------------------------------------------------
// Bilinear sampling. One 64-lane wave per (nq,cam) unit; lane = h*8 + d4,
// float4 along dh. Block = 256 threads = 4 units.
// ---------------------------------------------------------------------------
__global__ __launch_bounds__(256) void k_sample(const float* __restrict__ vproj,
                                                const float* __restrict__ refcam,
                                                const float* __restrict__ off,
                                                const float* __restrict__ aw,
                                                const float* __restrict__ valid,
                                                float* __restrict__ acc) {
  const int u = blockIdx.x * 4 + (threadIdx.x >> 6);
  const int lane = threadIdx.x & 63;
  const int h = lane >> 3;
  const int d4 = lane & 7;
  const int cam = u / kNQ;
  const int nq = u - cam * kNQ;

  float* op = acc + ((long long)(cam * kNQ + nq)) * kC + h * 32 + d4 * 4;

  if (valid[cam * kNQ + nq] == 0.f) {  // wave-uniform: whole unit invalid
    *reinterpret_cast<float4*>(op) = float4{0.f, 0.f, 0.f, 0.f};
    return;
  }

  static constexpr int SHH[4] = {64, 32, 16, 8};
  static constexpr int SHW[4] = {160, 80, 40, 20};
  static constexpr int LSI[4] = {0, 10240, 12800, 13440};

  const float* rcp = refcam + (long long)(cam * kNQ + nq) * 8;
  const float4 rcA = *reinterpret_cast<const float4*>(rcp);
  const float4 rcB = *reinterpret_cast<const float4*>(rcp + 4);
  const float* offp = off + (long long)nq * 256 + h * 32;
  const float* awp = aw + (long long)nq * 128 + h * 16;

  float4 acc4 = {0.f, 0.f, 0.f, 0.f};

#pragma unroll
  for (int l = 0; l < 4; ++l) {
    const int Hl = SHH[l];
    const int Wl = SHW[l];
    const float Hf = (float)Hl;
    const float Wf = (float)Wl;
    const float4 aw4 = *reinterpret_cast<const float4*>(awp + l * 4);
    const float4 ofA = *reinterpret_cast<const float4*>(offp + l * 8);
    const float4 ofB = *reinterpret_cast<const float4*>(offp + l * 8 + 4);
    const float* vf =
        vproj + ((long long)(cam * kH + h) * kNK + LSI[l]) * kDh + d4 * 4;

    const float rx[4] = {rcA.x, rcA.z, rcB.x, rcB.z};
    const float ry[4] = {rcA.y, rcA.w, rcB.y, rcB.w};
    const float ox[4] = {ofA.x, ofA.z, ofB.x, ofB.z};
    const float oy[4] = {ofA.y, ofA.w, ofB.y, ofB.w};
    const float wr[4] = {aw4.x, aw4.y, aw4.z, aw4.w};

#pragma unroll
    for (int r = 0; r < 4; ++r) {
      const float x = fmaf(rx[r], Wf, ox[r]) - 0.5f;
      const float y = fmaf(ry[r], Hf, oy[r]) - 0.5f;
      const float x0 = floorf(x);
      const float y0 = floorf(y);
      const float lx = x - x0;
      const float ly = y - y0;
      const int ix = (int)x0;
      const int iy = (int)y0;
      const int ix0 = min(max(ix, 0), Wl - 1);
      const int ix1 = min(max(ix + 1, 0), Wl - 1);
      const int iy0 = min(max(iy, 0), Hl - 1);
      const int iy1 = min(max(iy + 1, 0), Hl - 1);
      const bool bx0 = (ix >= 0) & (ix < Wl);
      const bool bx1 = (ix >= -1) & (ix + 1 < Wl);
      const bool by0 = (iy >= 0) & (iy < Hl);
      const bool by1 = (iy >= -1) & (iy + 1 < Hl);
      const float w = wr[r];
      const float wy0 = w * (1.f - ly);
      const float wy1 = w * ly;
      const float w00 = (by0 && bx0) ? wy0 * (1.f - lx) : 0.f;
      const float w01 = (by0 && bx1) ? wy0 * lx : 0.f;
      const float w10 = (by1 && bx0) ? wy1 * (1.f - lx) : 0.f;
      const float w11 = (by1 && bx1) ? wy1 * lx : 0.f;
      const float4 v00 = *reinterpret_cast<const float4*>(vf + (iy0 * Wl + ix0) * kDh);
      const float4 v01 = *reinterpret_cast<const float4*>(vf + (iy0 * Wl + ix1) * kDh);
      const float4 v10 = *reinterpret_cast<const float4*>(vf + (iy1 * Wl + ix0) * kDh);
      const float4 v11 = *reinterpret_cast<const float4*>(vf + (iy1 * Wl + ix1) * kDh);
      acc4.x = fmaf(w00, v00.x, fmaf(w01, v01.x, fmaf(w10, v10.x, fmaf(w11, v11.x, acc4.x))));
      acc4.y = fmaf(w00, v00.y, fmaf(w01, v01.y, fmaf(w10, v10.y, fmaf(w11, v11.y, acc4.y))));
      acc4.z = fmaf(w00, v00.z, fmaf(w01, v01.z, fmaf(w10, v10.z, fmaf(w11, v11.z, acc4.z))));
      acc4.w = fmaf(w00, v00.w, fmaf(w01, v01.w, fmaf(w10, v10.w, fmaf(w11, v11.w, acc4.w))));
    }
  }

  *reinterpret_cast<float4*>(op) = acc4;
}

// ---------------------------------------------------------------------------
// Masked mean over cameras.
// ---------------------------------------------------------------------------
__global__ __launch_bounds__(256) void k_combine(const float* __restrict__ acc,
                                                 const float* __restrict__ valid,
                                                 float* __restrict__ slots) {
  const int nq = blockIdx.x;
  const int c = threadIdx.x;
  float cnt = 0.f;
  float s = 0.f;
#pragma unroll
  for (int cam = 0; cam < kCams; ++cam) {
    const float v = valid[cam * kNQ + nq];
    cnt += v;
    s += acc[((long long)(cam * kNQ + nq)) * kC + c] * v;
  }
  slots[(long long)nq * kC + c] = s / fmaxf(cnt, 1.f);
}

}  // namespace

extern "C" void kernel_launch(void* const* d_in, const int* in_sizes, int n_in,
                              void* d_out, int out_size, void* d_ws, size_t ws_size,
                              hipStream_t stream) {
  (void)in_sizes; (void)n_in; (void)out_size; (void)ws_size;
  const float* query     = (const float*)d_in[0];
  const float* query_pos = (const float*)d_in[1];
  const float* value     = (const float*)d_in[2];
  const float* refpts    = (const float*)d_in[3];
  const float* l2i       = (const float*)d_in[4];
  const float* img_shape = (const float*)d_in[5];
  const float* W_val  = (const float*)d_in[8];
  const float* b_val  = (const float*)d_in[9];
  const float* W_samp = (const float*)d_in[10];
  const float* b_samp = (const float*)d_in[11];
  const float* W_attn = (const float*)d_in[12];
  const float* b_attn = (const float*)d_in[13];
  const float* W_dout = (const float*)d_in[14];
  const float* b_dout = (const float*)d_in[15];
  const float* W_out  = (const float*)d_in[16];
  const float* b_out  = (const float*)d_in[17];

  float* ws = (float*)d_ws;
  float* off    = ws;                      // 2,560,000 floats
  float* aw     = off + 2560000;           // 1,280,000
  float* refcam = aw + 1280000;            //   480,000
  float* valid  = refcam + 480000;         //    60,000
  float* vproj  = valid + 60000;           // 20,889,600
  float* acc    = vproj + 20889600;        // 15,360,000
  float* slots  = vproj;                   // alias: vproj dead after k_sample
  float* out    = (float*)d_out;

  // q-projections (q+qpos fused into staging)
  k_gemm2<512><<<dim3((kNQ + 31) / 32), 256, 0, stream>>>(query, query_pos, W_samp,
                                                          b_samp, nullptr, off, kNQ);
  k_gemm2<128><<<dim3((kNQ + 31) / 32), 64, 0, stream>>>(query, query_pos, W_attn,
                                                         b_attn, nullptr, aw, kNQ);
  k_softmax16<<<dim3(kNQ), 128, 0, stream>>>(aw);

  // camera projection + visibility
  k_proj_ref<<<dim3((kCams * kNQ + 255) / 256), 256, 0, stream>>>(refpts, l2i,
                                                                  img_shape, refcam,
                                                                  valid);
  // value projection
  k_gemm_vproj<<<dim3(kNK / 32, kCams), 128, 0, stream>>>(value, W_val, b_val, vproj);

  // bilinear sampling + weighted accumulation (4 units of 64 lanes per block)
  k_sample<<<dim3(kCams * kNQ / 4), 256, 0, stream>>>(vproj, refcam, off, aw, valid,
                                                      acc);

  // per-camera output projection (in-place on acc)
  k_gemm2<256><<<dim3((kCams * kNQ + 31) / 32), 128, 0, stream>>>(acc, nullptr, W_dout,
                                                                  b_dout, nullptr, acc,
                                                                  kCams * kNQ);
  // masked mean over cameras
  k_combine<<<dim3(kNQ), 256, 0, stream>>>(acc, valid, slots);

  // final projection + residual
  k_gemm2<256><<<dim3((kNQ + 31) / 32), 128, 0, stream>>>(slots, nullptr, W_out, b_out,
                                                          query, out, kNQ);
}

// Round 3
// 184.829 us; speedup vs baseline: 5.8037x; 3.4656x over previous
//
#include <hip/hip_runtime.h>

namespace {

typedef unsigned short u16;
typedef unsigned int u32;
typedef __attribute__((ext_vector_type(8))) short bf16x8;
typedef __attribute__((ext_vector_type(4))) float f32x4;

constexpr int kNQ   = 10000;
constexpr int kCams = 6;
constexpr int kC    = 256;
constexpr int kH    = 8;
constexpr int kNK   = 13600;
constexpr float kEps = 1e-5f;

__device__ __forceinline__ u16 f2b(float f) {
  u32 u = __float_as_uint(f);
  u += 0x7fffu + ((u >> 16) & 1u);   // RNE
  return (u16)(u >> 16);
}
__device__ __forceinline__ float b2f(u16 b) {
  return __uint_as_float(((u32)b) << 16);
}

// ---------------------------------------------------------------------------
// Transposed bf16 weight: Wt[n][k] = bf16(W[k][n]).  grid (N/32, 8), block 256
// ---------------------------------------------------------------------------
__global__ __launch_bounds__(256) void k_cvt_wT(const float* __restrict__ W,
                                                u16* __restrict__ Wt, int N) {
  __shared__ float t[32][33];
  const int bn = blockIdx.x;
  const int bk = blockIdx.y;
  const int tid = threadIdx.x;
#pragma unroll
  for (int e = 0; e < 4; ++e) {
    const int i = e * 256 + tid;
    const int kk = i >> 5, nn = i & 31;
    t[kk][nn] = W[(bk * 32 + kk) * N + bn * 32 + nn];
  }
  __syncthreads();
#pragma unroll
  for (int e = 0; e < 4; ++e) {
    const int i = e * 256 + tid;
    const int nn = i >> 5, kk = i & 31;
    Wt[(bn * 32 + nn) * 256 + bk * 32 + kk] = f2b(t[kk][nn]);
  }
}

// ---------------------------------------------------------------------------
// qpq[i] = bf16(a[i] + b[i]); 8 elems/thread
// ---------------------------------------------------------------------------
__global__ __launch_bounds__(256) void k_cvt_add(const float* __restrict__ a,
                                                 const float* __restrict__ b,
                                                 u16* __restrict__ out) {
  const int t = blockIdx.x * 256 + threadIdx.x;
  const int i = t * 8;
  const float4 x0 = *reinterpret_cast<const float4*>(a + i);
  const float4 x1 = *reinterpret_cast<const float4*>(a + i + 4);
  const float4 y0 = *reinterpret_cast<const float4*>(b + i);
  const float4 y1 = *reinterpret_cast<const float4*>(b + i + 4);
  ushort4 lo, hi;
  lo.x = f2b(x0.x + y0.x); lo.y = f2b(x0.y + y0.y);
  lo.z = f2b(x0.z + y0.z); lo.w = f2b(x0.w + y0.w);
  hi.x = f2b(x1.x + y1.x); hi.y = f2b(x1.y + y1.y);
  hi.z = f2b(x1.z + y1.z); hi.w = f2b(x1.w + y1.w);
  *reinterpret_cast<ushort4*>(out + i) = lo;
  *reinterpret_cast<ushort4*>(out + i + 4) = hi;
}

// ---------------------------------------------------------------------------
// A_val[cam*NK+n][k] = bf16(value[n][cam][k]); 8 elems/thread
// ---------------------------------------------------------------------------
__global__ __launch_bounds__(256) void k_cvt_value(const float* __restrict__ value,
                                                   u16* __restrict__ Aval) {
  const int t = blockIdx.x * 256 + threadIdx.x;
  const int row = t >> 5;
  const int j = (t & 31) << 3;
  const int cam = row / kNK;
  const int n = row - cam * kNK;
  const float* src = value + ((long long)(n * kCams + cam) * 256) + j;
  const float4 a = *reinterpret_cast<const float4*>(src);
  const float4 b = *reinterpret_cast<const float4*>(src + 4);
  ushort4 lo, hi;
  lo.x = f2b(a.x); lo.y = f2b(a.y); lo.z = f2b(a.z); lo.w = f2b(a.w);
  hi.x = f2b(b.x); hi.y = f2b(b.y); hi.z = f2b(b.z); hi.w = f2b(b.w);
  u16* dst = Aval + (long long)row * 256 + j;
  *reinterpret_cast<ushort4*>(dst) = lo;
  *reinterpret_cast<ushort4*>(dst + 4) = hi;
}

// ---------------------------------------------------------------------------
// MFMA GEMM: out[M][Ntot] = A_bf16[M][256] @ Wt_bf16[Ntot][256]^T + bias
//            (+ addend fp32).  Tile 128x128xK64, 4 waves, XOR-swizzled LDS.
// ---------------------------------------------------------------------------
template <bool OUT_BF16, bool HAS_ADD>
__global__ __launch_bounds__(256) void k_mfma(const u16* __restrict__ A,
                                              const u16* __restrict__ Wt,
                                              const float* __restrict__ bias,
                                              const float* __restrict__ addend,
                                              void* __restrict__ outp,
                                              int M, int Ntot) {
  __shared__ u16 As[128 * 64];
  __shared__ u16 Bs[128 * 64];
  const int tid = threadIdx.x;
  const int m0 = blockIdx.x * 128;
  const int n0 = blockIdx.y * 128;
  const int wave = tid >> 6;
  const int lane = tid & 63;
  const int wr = wave >> 1;
  const int wc = wave & 1;
  const int lr = lane & 15;
  const int lg = lane >> 4;

  f32x4 acc[4][4] = {};

  const int srow = tid >> 3;   // 0..31
  const int slot = tid & 7;

  for (int kt = 0; kt < 4; ++kt) {
    const int k0 = kt * 64;
#pragma unroll
    for (int c = 0; c < 4; ++c) {
      const int rowA = c * 32 + srow;
      const int sw = ((slot ^ (rowA & 7)) << 3);
      const bf16x8 va = *reinterpret_cast<const bf16x8*>(
          A + (long long)(m0 + rowA) * 256 + k0 + slot * 8);
      *reinterpret_cast<bf16x8*>(&As[rowA * 64 + sw]) = va;
      const bf16x8 vb = *reinterpret_cast<const bf16x8*>(
          Wt + (long long)(n0 + rowA) * 256 + k0 + slot * 8);
      *reinterpret_cast<bf16x8*>(&Bs[rowA * 64 + sw]) = vb;
    }
    __syncthreads();
#pragma unroll
    for (int ks = 0; ks < 2; ++ks) {
      bf16x8 af[4], bfr[4];
#pragma unroll
      for (int mi = 0; mi < 4; ++mi) {
        const int r = wr * 64 + mi * 16 + lr;
        const int s = ks * 4 + lg;
        af[mi] = *reinterpret_cast<const bf16x8*>(&As[r * 64 + ((s ^ (r & 7)) << 3)]);
      }
#pragma unroll
      for (int ni = 0; ni < 4; ++ni) {
        const int r = wc * 64 + ni * 16 + lr;
        const int s = ks * 4 + lg;
        bfr[ni] = *reinterpret_cast<const bf16x8*>(&Bs[r * 64 + ((s ^ (r & 7)) << 3)]);
      }
#pragma unroll
      for (int mi = 0; mi < 4; ++mi)
#pragma unroll
        for (int ni = 0; ni < 4; ++ni)
          acc[mi][ni] = __builtin_amdgcn_mfma_f32_16x16x32_bf16(af[mi], bfr[ni],
                                                                acc[mi][ni], 0, 0, 0);
    }
    __syncthreads();
  }

#pragma unroll
  for (int mi = 0; mi < 4; ++mi) {
#pragma unroll
    for (int reg = 0; reg < 4; ++reg) {
      const int row = m0 + wr * 64 + mi * 16 + lg * 4 + reg;
      if (row < M) {
#pragma unroll
        for (int ni = 0; ni < 4; ++ni) {
          const int col = n0 + wc * 64 + ni * 16 + lr;
          float v = acc[mi][ni][reg] + bias[col];
          if (HAS_ADD) v += addend[(long long)row * Ntot + col];
          if (OUT_BF16)
            ((u16*)outp)[(long long)row * Ntot + col] = f2b(v);
          else
            ((float*)outp)[(long long)row * Ntot + col] = v;
        }
      }
    }
  }
}

// ---------------------------------------------------------------------------
// Softmax over each 16-wide group (per head), 128 logits per query.
// ---------------------------------------------------------------------------
__global__ __launch_bounds__(128) void k_softmax16(float* __restrict__ aw) {
  const int nq = blockIdx.x;
  const int t = threadIdx.x;
  float v = aw[(long long)nq * 128 + t];
  float mx = v;
#pragma unroll
  for (int s = 1; s < 16; s <<= 1) mx = fmaxf(mx, __shfl_xor(mx, s));
  const float e = expf(v - mx);
  float sm = e;
#pragma unroll
  for (int s = 1; s < 16; s <<= 1) sm += __shfl_xor(sm, s);
  aw[(long long)nq * 128 + t] = e / sm;
}

// ---------------------------------------------------------------------------
// Camera projection of reference points + visibility mask.
// ---------------------------------------------------------------------------
__global__ __launch_bounds__(256) void k_proj_ref(const float* __restrict__ refpts,
                                                  const float* __restrict__ l2i,
                                                  const float* __restrict__ img_shape,
                                                  float* __restrict__ refcam,
                                                  float* __restrict__ valid) {
  const int idx = blockIdx.x * blockDim.x + threadIdx.x;
  if (idx >= kCams * kNQ) return;
  const int cam = idx / kNQ;
  const int nq = idx - cam * kNQ;
  const float* Mp = l2i + cam * 12;
  float m[12];
#pragma unroll
  for (int i = 0; i < 12; ++i) m[i] = Mp[i];
  const float ih = img_shape[cam * 2 + 0];
  const float iw = img_shape[cam * 2 + 1];
  float anyv = 0.f;
  float* rcout = refcam + (long long)idx * 8;
#pragma unroll
  for (int r = 0; r < 4; ++r) {
    const float* rp = refpts + ((long long)nq * 4 + r) * 3;
    const float X = rp[0] * 102.4f + (-51.2f);
    const float Y = rp[1] * 102.4f + (-51.2f);
    const float Z = rp[2] * 8.0f + (-5.0f);
    const float cx = m[0] * X + m[1] * Y + m[2] * Z + m[3];
    const float cy = m[4] * X + m[5] * Y + m[6] * Z + m[7];
    const float cz = m[8] * X + m[9] * Y + m[10] * Z + m[11];
    const float zc = fmaxf(cz, kEps);
    const float xn = cx / zc / iw;
    const float yn = cy / zc / ih;
    rcout[r * 2 + 0] = xn;
    rcout[r * 2 + 1] = yn;
    if ((cz > kEps) && (xn > 0.f) && (xn < 1.f) && (yn > 0.f) && (yn < 1.f)) anyv = 1.f;
  }
  valid[idx] = anyv;
}

// ---------------------------------------------------------------------------
// Bilinear sampling; vproj is bf16 [cam][n][256]. One wave per (nq,cam);
// lane = h*8 + d4 (float4-of-bf16 along dh). acc written as bf16.
// ---------------------------------------------------------------------------
__global__ __launch_bounds__(256) void k_sample(const u16* __restrict__ vproj,
                                                const float* __restrict__ refcam,
                                                const float* __restrict__ off,
                                                const float* __restrict__ aw,
                                                const float* __restrict__ valid,
                                                u16* __restrict__ acc) {
  const int u = blockIdx.x * 4 + (threadIdx.x >> 6);
  const int lane = threadIdx.x & 63;
  const int h = lane >> 3;
  const int d4 = lane & 7;
  const int cam = u / kNQ;
  const int nq = u - cam * kNQ;

  u16* op = acc + (long long)(cam * kNQ + nq) * kC + h * 32 + d4 * 4;

  if (valid[cam * kNQ + nq] == 0.f) {
    *reinterpret_cast<ushort4*>(op) = ushort4{0, 0, 0, 0};
    return;
  }

  static constexpr int SHH[4] = {64, 32, 16, 8};
  static constexpr int SHW[4] = {160, 80, 40, 20};
  static constexpr int LSI[4] = {0, 10240, 12800, 13440};

  const float* rcp = refcam + (long long)(cam * kNQ + nq) * 8;
  const float4 rcA = *reinterpret_cast<const float4*>(rcp);
  const float4 rcB = *reinterpret_cast<const float4*>(rcp + 4);
  const float* offp = off + (long long)nq * 256 + h * 32;
  const float* awp = aw + (long long)nq * 128 + h * 16;

  float4 acc4 = {0.f, 0.f, 0.f, 0.f};

#pragma unroll
  for (int l = 0; l < 4; ++l) {
    const int Hl = SHH[l];
    const int Wl = SHW[l];
    const float Hf = (float)Hl;
    const float Wf = (float)Wl;
    const float4 aw4 = *reinterpret_cast<const float4*>(awp + l * 4);
    const float4 ofA = *reinterpret_cast<const float4*>(offp + l * 8);
    const float4 ofB = *reinterpret_cast<const float4*>(offp + l * 8 + 4);
    const u16* vf = vproj + ((long long)(cam * kNK + LSI[l])) * 256 + h * 32 + d4 * 4;

    const float rx[4] = {rcA.x, rcA.z, rcB.x, rcB.z};
    const float ry[4] = {rcA.y, rcA.w, rcB.y, rcB.w};
    const float ox[4] = {ofA.x, ofA.z, ofB.x, ofB.z};
    const float oy[4] = {ofA.y, ofA.w, ofB.y, ofB.w};
    const float wr[4] = {aw4.x, aw4.y, aw4.z, aw4.w};

#pragma unroll
    for (int r = 0; r < 4; ++r) {
      const float x = fmaf(rx[r], Wf, ox[r]) - 0.5f;
      const float y = fmaf(ry[r], Hf, oy[r]) - 0.5f;
      const float x0 = floorf(x);
      const float y0 = floorf(y);
      const float lx = x - x0;
      const float ly = y - y0;
      const int ix = (int)x0;
      const int iy = (int)y0;
      const int ix0 = min(max(ix, 0), Wl - 1);
      const int ix1 = min(max(ix + 1, 0), Wl - 1);
      const int iy0 = min(max(iy, 0), Hl - 1);
      const int iy1 = min(max(iy + 1, 0), Hl - 1);
      const bool bx0 = (ix >= 0) & (ix < Wl);
      const bool bx1 = (ix >= -1) & (ix + 1 < Wl);
      const bool by0 = (iy >= 0) & (iy < Hl);
      const bool by1 = (iy >= -1) & (iy + 1 < Hl);
      const float w = wr[r];
      const float wy0 = w * (1.f - ly);
      const float wy1 = w * ly;
      const float w00 = (by0 && bx0) ? wy0 * (1.f - lx) : 0.f;
      const float w01 = (by0 && bx1) ? wy0 * lx : 0.f;
      const float w10 = (by1 && bx0) ? wy1 * (1.f - lx) : 0.f;
      const float w11 = (by1 && bx1) ? wy1 * lx : 0.f;
      const ushort4 v00 = *reinterpret_cast<const ushort4*>(vf + (iy0 * Wl + ix0) * 256);
      const ushort4 v01 = *reinterpret_cast<const ushort4*>(vf + (iy0 * Wl + ix1) * 256);
      const ushort4 v10 = *reinterpret_cast<const ushort4*>(vf + (iy1 * Wl + ix0) * 256);
      const ushort4 v11 = *reinterpret_cast<const ushort4*>(vf + (iy1 * Wl + ix1) * 256);
      acc4.x = fmaf(w00, b2f(v00.x), fmaf(w01, b2f(v01.x), fmaf(w10, b2f(v10.x), fmaf(w11, b2f(v11.x), acc4.x))));
      acc4.y = fmaf(w00, b2f(v00.y), fmaf(w01, b2f(v01.y), fmaf(w10, b2f(v10.y), fmaf(w11, b2f(v11.y), acc4.y))));
      acc4.z = fmaf(w00, b2f(v00.z), fmaf(w01, b2f(v01.z), fmaf(w10, b2f(v10.z), fmaf(w11, b2f(v11.z), acc4.z))));
      acc4.w = fmaf(w00, b2f(v00.w), fmaf(w01, b2f(v01.w), fmaf(w10, b2f(v10.w), fmaf(w11, b2f(v11.w), acc4.w))));
    }
  }

  ushort4 o;
  o.x = f2b(acc4.x); o.y = f2b(acc4.y); o.z = f2b(acc4.z); o.w = f2b(acc4.w);
  *reinterpret_cast<ushort4*>(op) = o;
}

// ---------------------------------------------------------------------------
// Masked mean over cameras; dout bf16 in, slots bf16 out.
// ---------------------------------------------------------------------------
__global__ __launch_bounds__(256) void k_combine(const u16* __restrict__ dout,
                                                 const float* __restrict__ valid,
                                                 u16* __restrict__ slots) {
  const int nq = blockIdx.x;
  const int c = threadIdx.x;
  float cnt = 0.f;
  float s = 0.f;
#pragma unroll
  for (int cam = 0; cam < kCams; ++cam) {
    const float v = valid[cam * kNQ + nq];
    cnt += v;
    s += b2f(dout[(long long)(cam * kNQ + nq) * kC + c]) * v;
  }
  slots[(long long)nq * kC + c] = f2b(s / fmaxf(cnt, 1.f));
}

}  // namespace

extern "C" void kernel_launch(void* const* d_in, const int* in_sizes, int n_in,
                              void* d_out, int out_size, void* d_ws, size_t ws_size,
                              hipStream_t stream) {
  (void)in_sizes; (void)n_in; (void)out_size; (void)ws_size;
  const float* query     = (const float*)d_in[0];
  const float* query_pos = (const float*)d_in[1];
  const float* value     = (const float*)d_in[2];
  const float* refpts    = (const float*)d_in[3];
  const float* l2i       = (const float*)d_in[4];
  const float* img_shape = (const float*)d_in[5];
  const float* W_val  = (const float*)d_in[8];
  const float* b_val  = (const float*)d_in[9];
  const float* W_samp = (const float*)d_in[10];
  const float* b_samp = (const float*)d_in[11];
  const float* W_attn = (const float*)d_in[12];
  const float* b_attn = (const float*)d_in[13];
  const float* W_dout = (const float*)d_in[14];
  const float* b_dout = (const float*)d_in[15];
  const float* W_out  = (const float*)d_in[16];
  const float* b_out  = (const float*)d_in[17];

  // workspace layout (bytes, all 16B-aligned)
  char* p = (char*)d_ws;
  float* off    = (float*)p;            p += 10240000;  // [10000][256] f32
  float* aw     = (float*)p;            p += 5120000;   // [10000][128] f32
  float* refcam = (float*)p;            p += 1920000;   // [6*10000][8] f32
  float* valid  = (float*)p;            p += 240000;    // [6*10000] f32
  u16*   vproj  = (u16*)p;              p += 41779200;  // [6*13600][256] bf16
  u16*   acc    = (u16*)p;              p += 30720000;  // [60000][256] bf16
  u16*   slots  = (u16*)p;              p += 5120000;   // [10000][256] bf16
  u16*   qpq    = (u16*)p;              p += 5120000;   // [10000][256] bf16
  u16*   WtVal  = (u16*)p;              p += 131072;
  u16*   WtSamp = (u16*)p;              p += 131072;
  u16*   WtAttn = (u16*)p;              p += 65536;
  u16*   WtDout = (u16*)p;              p += 131072;
  u16*   WtOut  = (u16*)p;              p += 131072;
  u16*   Aval   = (u16*)p;              p += 41779200;  // [81600][256] bf16
  u16*   doutb  = Aval;                 // alias: Aval dead after vproj GEMM
  float* out    = (float*)d_out;

  // weight transposes (bf16)
  k_cvt_wT<<<dim3(8, 8), 256, 0, stream>>>(W_val, WtVal, 256);
  k_cvt_wT<<<dim3(8, 8), 256, 0, stream>>>(W_samp, WtSamp, 256);
  k_cvt_wT<<<dim3(4, 8), 256, 0, stream>>>(W_attn, WtAttn, 128);
  k_cvt_wT<<<dim3(8, 8), 256, 0, stream>>>(W_dout, WtDout, 256);
  k_cvt_wT<<<dim3(8, 8), 256, 0, stream>>>(W_out, WtOut, 256);

  // q + q_pos -> bf16 ; value permute -> bf16
  k_cvt_add<<<dim3(1250), 256, 0, stream>>>(query, query_pos, qpq);
  k_cvt_value<<<dim3(10200), 256, 0, stream>>>(value, Aval);

  // camera projection + visibility
  k_proj_ref<<<dim3((kCams * kNQ + 255) / 256), 256, 0, stream>>>(refpts, l2i,
                                                                  img_shape, refcam,
                                                                  valid);

  // sampling-offset / attention-weight projections (MFMA)
  k_mfma<false, false><<<dim3(79, 2), 256, 0, stream>>>(qpq, WtSamp, b_samp, nullptr,
                                                        off, kNQ, 256);
  k_mfma<false, false><<<dim3(79, 1), 256, 0, stream>>>(qpq, WtAttn, b_attn, nullptr,
                                                        aw, kNQ, 128);
  k_softmax16<<<dim3(kNQ), 128, 0, stream>>>(aw);

  // value projection (MFMA, bf16 out, [cam][n][256])
  k_mfma<true, false><<<dim3(638, 2), 256, 0, stream>>>(Aval, WtVal, b_val, nullptr,
                                                        vproj, kNK * kCams, 256);

  // bilinear sampling -> acc bf16
  k_sample<<<dim3(kCams * kNQ / 4), 256, 0, stream>>>(vproj, refcam, off, aw, valid,
                                                      acc);

  // per-camera output projection (MFMA, bf16 out)
  k_mfma<true, false><<<dim3(469, 2), 256, 0, stream>>>(acc, WtDout, b_dout, nullptr,
                                                        doutb, kCams * kNQ, 256);

  // masked mean over cameras -> slots bf16
  k_combine<<<dim3(kNQ), 256, 0, stream>>>(doutb, valid, slots);

  // final projection + residual (fp32 out)
  k_mfma<false, true><<<dim3(79, 2), 256, 0, stream>>>(slots, WtOut, b_out, query,
                                                       out, kNQ, 256);
}

// Round 4
// 151.729 us; speedup vs baseline: 7.0698x; 1.2182x over previous
//
#include <hip/hip_runtime.h>

namespace {

typedef unsigned short u16;
typedef unsigned int u32;
typedef __attribute__((ext_vector_type(8))) short bf16x8;
typedef __attribute__((ext_vector_type(4))) float f32x4;

constexpr int kNQ   = 10000;
constexpr int kCams = 6;
constexpr int kC    = 256;
constexpr int kNK   = 13600;
constexpr float kEps = 1e-5f;

__device__ __forceinline__ u16 f2b(float f) {
  u32 u = __float_as_uint(f);
  u += 0x7fffu + ((u >> 16) & 1u);   // RNE
  return (u16)(u >> 16);
}
__device__ __forceinline__ float b2f(u16 b) {
  return __uint_as_float(((u32)b) << 16);
}

// ---------------------------------------------------------------------------
// All 5 weight transposes in one launch. bn-blocks: [0,8)=val [8,16)=samp
// [16,20)=attn(->rows 256..383 of samp-attn buffer) [20,28)=dout [28,36)=out
// ---------------------------------------------------------------------------
__global__ __launch_bounds__(256) void k_cvt_w_all(
    const float* __restrict__ w_val, const float* __restrict__ w_samp,
    const float* __restrict__ w_attn, const float* __restrict__ w_dout,
    const float* __restrict__ w_out, u16* __restrict__ t_val,
    u16* __restrict__ t_sa, u16* __restrict__ t_dout, u16* __restrict__ t_out) {
  __shared__ float t[32][33];
  const int bn = blockIdx.x;
  const int bk = blockIdx.y;
  const int tid = threadIdx.x;
  const float* W; u16* Wt; int N, lb;
  if (bn < 8)       { W = w_val;  Wt = t_val;            N = 256; lb = bn; }
  else if (bn < 16) { W = w_samp; Wt = t_sa;             N = 256; lb = bn - 8; }
  else if (bn < 20) { W = w_attn; Wt = t_sa + 256 * 256; N = 128; lb = bn - 16; }
  else if (bn < 28) { W = w_dout; Wt = t_dout;           N = 256; lb = bn - 20; }
  else              { W = w_out;  Wt = t_out;            N = 256; lb = bn - 28; }
#pragma unroll
  for (int e = 0; e < 4; ++e) {
    const int i = e * 256 + tid;
    const int kk = i >> 5, nn = i & 31;
    t[kk][nn] = W[(bk * 32 + kk) * N + lb * 32 + nn];
  }
  __syncthreads();
#pragma unroll
  for (int e = 0; e < 4; ++e) {
    const int i = e * 256 + tid;
    const int nn = i >> 5, kk = i & 31;
    Wt[(lb * 32 + nn) * 256 + bk * 32 + kk] = f2b(t[kk][nn]);
  }
}

// ---------------------------------------------------------------------------
// qpq[i] = bf16(a[i] + b[i]); 8 elems/thread
// ---------------------------------------------------------------------------
__global__ __launch_bounds__(256) void k_cvt_add(const float* __restrict__ a,
                                                 const float* __restrict__ b,
                                                 u16* __restrict__ out) {
  const int t = blockIdx.x * 256 + threadIdx.x;
  const int i = t * 8;
  const float4 x0 = *reinterpret_cast<const float4*>(a + i);
  const float4 x1 = *reinterpret_cast<const float4*>(a + i + 4);
  const float4 y0 = *reinterpret_cast<const float4*>(b + i);
  const float4 y1 = *reinterpret_cast<const float4*>(b + i + 4);
  ushort4 lo, hi;
  lo.x = f2b(x0.x + y0.x); lo.y = f2b(x0.y + y0.y);
  lo.z = f2b(x0.z + y0.z); lo.w = f2b(x0.w + y0.w);
  hi.x = f2b(x1.x + y1.x); hi.y = f2b(x1.y + y1.y);
  hi.z = f2b(x1.z + y1.z); hi.w = f2b(x1.w + y1.w);
  *reinterpret_cast<ushort4*>(out + i) = lo;
  *reinterpret_cast<ushort4*>(out + i + 4) = hi;
}

// ---------------------------------------------------------------------------
// MFMA GEMM: out[M][Ntot] = A_bf16[M][256] @ Wt_bf16[Ntot][256]^T + bias
// Tile 128x128xK64, 4 waves, XOR-swizzled LDS. Optional split bias (cols >=
// nsplit take bias2), per-row bias scale, fp32 addend, bf16 or f32 out.
// ---------------------------------------------------------------------------
template <bool OUT_BF16, bool HAS_ADD>
__global__ __launch_bounds__(256) void k_mfma(const u16* __restrict__ A,
                                              const u16* __restrict__ Wt,
                                              const float* __restrict__ bias,
                                              const float* __restrict__ bias2,
                                              int nsplit,
                                              const float* __restrict__ bias_scale,
                                              const float* __restrict__ addend,
                                              void* __restrict__ outp,
                                              int M, int Ntot) {
  __shared__ u16 As[128 * 64];
  __shared__ u16 Bs[128 * 64];
  const int tid = threadIdx.x;
  const int m0 = blockIdx.x * 128;
  const int n0 = blockIdx.y * 128;
  const int wave = tid >> 6;
  const int lane = tid & 63;
  const int wr = wave >> 1;
  const int wc = wave & 1;
  const int lr = lane & 15;
  const int lg = lane >> 4;

  f32x4 acc[4][4] = {};

  const int srow = tid >> 3;   // 0..31
  const int slot = tid & 7;

  for (int kt = 0; kt < 4; ++kt) {
    const int k0 = kt * 64;
#pragma unroll
    for (int c = 0; c < 4; ++c) {
      const int rowA = c * 32 + srow;
      const int sw = ((slot ^ (rowA & 7)) << 3);
      const int ra = min(m0 + rowA, M - 1);
      const bf16x8 va = *reinterpret_cast<const bf16x8*>(
          A + (long long)ra * 256 + k0 + slot * 8);
      *reinterpret_cast<bf16x8*>(&As[rowA * 64 + sw]) = va;
      const bf16x8 vb = *reinterpret_cast<const bf16x8*>(
          Wt + (long long)(n0 + rowA) * 256 + k0 + slot * 8);
      *reinterpret_cast<bf16x8*>(&Bs[rowA * 64 + sw]) = vb;
    }
    __syncthreads();
#pragma unroll
    for (int ks = 0; ks < 2; ++ks) {
      bf16x8 af[4], bfr[4];
#pragma unroll
      for (int mi = 0; mi < 4; ++mi) {
        const int r = wr * 64 + mi * 16 + lr;
        const int s = ks * 4 + lg;
        af[mi] = *reinterpret_cast<const bf16x8*>(&As[r * 64 + ((s ^ (r & 7)) << 3)]);
      }
#pragma unroll
      for (int ni = 0; ni < 4; ++ni) {
        const int r = wc * 64 + ni * 16 + lr;
        const int s = ks * 4 + lg;
        bfr[ni] = *reinterpret_cast<const bf16x8*>(&Bs[r * 64 + ((s ^ (r & 7)) << 3)]);
      }
#pragma unroll
      for (int mi = 0; mi < 4; ++mi)
#pragma unroll
        for (int ni = 0; ni < 4; ++ni)
          acc[mi][ni] = __builtin_amdgcn_mfma_f32_16x16x32_bf16(af[mi], bfr[ni],
                                                                acc[mi][ni], 0, 0, 0);
    }
    __syncthreads();
  }

#pragma unroll
  for (int mi = 0; mi < 4; ++mi) {
#pragma unroll
    for (int reg = 0; reg < 4; ++reg) {
      const int row = m0 + wr * 64 + mi * 16 + lg * 4 + reg;
      if (row < M) {
        const float bs = bias_scale ? bias_scale[row] : 1.f;
#pragma unroll
        for (int ni = 0; ni < 4; ++ni) {
          const int col = n0 + wc * 64 + ni * 16 + lr;
          const float b = (bias2 && col >= nsplit) ? bias2[col - nsplit] : bias[col];
          float v = acc[mi][ni][reg] + b * bs;
          if (HAS_ADD) v += addend[(long long)row * Ntot + col];
          if (OUT_BF16)
            ((u16*)outp)[(long long)row * Ntot + col] = f2b(v);
          else
            ((float*)outp)[(long long)row * Ntot + col] = v;
        }
      }
    }
  }
}

// ---------------------------------------------------------------------------
// Value-projection MFMA GEMM with fused f32->bf16 A staging + [n][cam]->row
// remap: row = cam*kNK + n  reads value[(n*kCams+cam)*256 + k].
// ---------------------------------------------------------------------------
__global__ __launch_bounds__(256) void k_mfma_vproj(const float* __restrict__ value,
                                                    const u16* __restrict__ Wt,
                                                    const float* __restrict__ bias,
                                                    u16* __restrict__ outp) {
  constexpr int M = kNK * kCams;
  __shared__ u16 As[128 * 64];
  __shared__ u16 Bs[128 * 64];
  const int tid = threadIdx.x;
  const int m0 = blockIdx.x * 128;
  const int n0 = blockIdx.y * 128;
  const int wave = tid >> 6;
  const int lane = tid & 63;
  const int wr = wave >> 1;
  const int wc = wave & 1;
  const int lr = lane & 15;
  const int lg = lane >> 4;

  f32x4 acc[4][4] = {};

  const int srow = tid >> 3;
  const int slot = tid & 7;

  for (int kt = 0; kt < 4; ++kt) {
    const int k0 = kt * 64;
#pragma unroll
    for (int c = 0; c < 4; ++c) {
      const int rowA = c * 32 + srow;
      const int sw = ((slot ^ (rowA & 7)) << 3);
      const int g = min(m0 + rowA, M - 1);
      const int cam = g / kNK;
      const int n = g - cam * kNK;
      const float* src = value + ((long long)(n * kCams + cam)) * 256 + k0 + slot * 8;
      const float4 a = *reinterpret_cast<const float4*>(src);
      const float4 b = *reinterpret_cast<const float4*>(src + 4);
      bf16x8 v;
      v[0] = (short)f2b(a.x); v[1] = (short)f2b(a.y);
      v[2] = (short)f2b(a.z); v[3] = (short)f2b(a.w);
      v[4] = (short)f2b(b.x); v[5] = (short)f2b(b.y);
      v[6] = (short)f2b(b.z); v[7] = (short)f2b(b.w);
      *reinterpret_cast<bf16x8*>(&As[rowA * 64 + sw]) = v;
      const bf16x8 vb = *reinterpret_cast<const bf16x8*>(
          Wt + (long long)(n0 + rowA) * 256 + k0 + slot * 8);
      *reinterpret_cast<bf16x8*>(&Bs[rowA * 64 + sw]) = vb;
    }
    __syncthreads();
#pragma unroll
    for (int ks = 0; ks < 2; ++ks) {
      bf16x8 af[4], bfr[4];
#pragma unroll
      for (int mi = 0; mi < 4; ++mi) {
        const int r = wr * 64 + mi * 16 + lr;
        const int s = ks * 4 + lg;
        af[mi] = *reinterpret_cast<const bf16x8*>(&As[r * 64 + ((s ^ (r & 7)) << 3)]);
      }
#pragma unroll
      for (int ni = 0; ni < 4; ++ni) {
        const int r = wc * 64 + ni * 16 + lr;
        const int s = ks * 4 + lg;
        bfr[ni] = *reinterpret_cast<const bf16x8*>(&Bs[r * 64 + ((s ^ (r & 7)) << 3)]);
      }
#pragma unroll
      for (int mi = 0; mi < 4; ++mi)
#pragma unroll
        for (int ni = 0; ni < 4; ++ni)
          acc[mi][ni] = __builtin_amdgcn_mfma_f32_16x16x32_bf16(af[mi], bfr[ni],
                                                                acc[mi][ni], 0, 0, 0);
    }
    __syncthreads();
  }

#pragma unroll
  for (int mi = 0; mi < 4; ++mi) {
#pragma unroll
    for (int reg = 0; reg < 4; ++reg) {
      const int row = m0 + wr * 64 + mi * 16 + lg * 4 + reg;
      if (row < M) {
#pragma unroll
        for (int ni = 0; ni < 4; ++ni) {
          const int col = n0 + wc * 64 + ni * 16 + lr;
          outp[(long long)row * 256 + col] = f2b(acc[mi][ni][reg] + bias[col]);
        }
      }
    }
  }
}

// ---------------------------------------------------------------------------
// Softmax over each 16-wide group; logits live at offaw[nq*384 + 256 + t].
// ---------------------------------------------------------------------------
__global__ __launch_bounds__(128) void k_softmax16(float* __restrict__ offaw) {
  const int nq = blockIdx.x;
  const int t = threadIdx.x;
  float* p = offaw + (long long)nq * 384 + 256 + t;
  float v = *p;
  float mx = v;
#pragma unroll
  for (int s = 1; s < 16; s <<= 1) mx = fmaxf(mx, __shfl_xor(mx, s));
  const float e = expf(v - mx);
  float sm = e;
#pragma unroll
  for (int s = 1; s < 16; s <<= 1) sm += __shfl_xor(sm, s);
  *p = e / sm;
}

// ---------------------------------------------------------------------------
// Camera projection of reference points + visibility mask.
// ---------------------------------------------------------------------------
__global__ __launch_bounds__(256) void k_proj_ref(const float* __restrict__ refpts,
                                                  const float* __restrict__ l2i,
                                                  const float* __restrict__ img_shape,
                                                  float* __restrict__ refcam,
                                                  float* __restrict__ valid) {
  const int idx = blockIdx.x * blockDim.x + threadIdx.x;
  if (idx >= kCams * kNQ) return;
  const int cam = idx / kNQ;
  const int nq = idx - cam * kNQ;
  const float* Mp = l2i + cam * 12;
  float m[12];
#pragma unroll
  for (int i = 0; i < 12; ++i) m[i] = Mp[i];
  const float ih = img_shape[cam * 2 + 0];
  const float iw = img_shape[cam * 2 + 1];
  float anyv = 0.f;
  float* rcout = refcam + (long long)idx * 8;
#pragma unroll
  for (int r = 0; r < 4; ++r) {
    const float* rp = refpts + ((long long)nq * 4 + r) * 3;
    const float X = rp[0] * 102.4f + (-51.2f);
    const float Y = rp[1] * 102.4f + (-51.2f);
    const float Z = rp[2] * 8.0f + (-5.0f);
    const float cx = m[0] * X + m[1] * Y + m[2] * Z + m[3];
    const float cy = m[4] * X + m[5] * Y + m[6] * Z + m[7];
    const float cz = m[8] * X + m[9] * Y + m[10] * Z + m[11];
    const float zc = fmaxf(cz, kEps);
    const float xn = cx / zc / iw;
    const float yn = cy / zc / ih;
    rcout[r * 2 + 0] = xn;
    rcout[r * 2 + 1] = yn;
    if ((cz > kEps) && (xn > 0.f) && (xn < 1.f) && (yn > 0.f) && (yn < 1.f)) anyv = 1.f;
  }
  valid[idx] = anyv;
}

// ---------------------------------------------------------------------------
// Bilinear sampling with fused masked camera-mean. One wave per nq; lane =
// h*8 + d4. Loops cameras with wave-uniform valid skip; accumulates the
// camera sum in registers; writes pre[nq][256] bf16 and cflag[nq].
// ---------------------------------------------------------------------------
__global__ __launch_bounds__(256) void k_sample(const u16* __restrict__ vproj,
                                                const float* __restrict__ refcam,
                                                const float* __restrict__ offaw,
                                                const float* __restrict__ valid,
                                                u16* __restrict__ pre,
                                                float* __restrict__ cflag) {
  const int nq = blockIdx.x * 4 + (threadIdx.x >> 6);
  const int lane = threadIdx.x & 63;
  const int h = lane >> 3;
  const int d4 = lane & 7;

  static constexpr int SHH[4] = {64, 32, 16, 8};
  static constexpr int SHW[4] = {160, 80, 40, 20};
  static constexpr int LSI[4] = {0, 10240, 12800, 13440};

  const float* offp = offaw + (long long)nq * 384 + h * 32;
  const float* awp = offaw + (long long)nq * 384 + 256 + h * 16;

  float4 acc4 = {0.f, 0.f, 0.f, 0.f};
  float count = 0.f;

  for (int cam = 0; cam < kCams; ++cam) {
    const float vl = valid[cam * kNQ + nq];
    if (vl == 0.f) continue;  // wave-uniform skip
    count += 1.f;

    const float* rcp = refcam + (long long)(cam * kNQ + nq) * 8;
    const float4 rcA = *reinterpret_cast<const float4*>(rcp);
    const float4 rcB = *reinterpret_cast<const float4*>(rcp + 4);
    const float rx[4] = {rcA.x, rcA.z, rcB.x, rcB.z};
    const float ry[4] = {rcA.y, rcA.w, rcB.y, rcB.w};

#pragma unroll
    for (int l = 0; l < 4; ++l) {
      const int Hl = SHH[l];
      const int Wl = SHW[l];
      const float Hf = (float)Hl;
      const float Wf = (float)Wl;
      const float4 aw4 = *reinterpret_cast<const float4*>(awp + l * 4);
      const float4 ofA = *reinterpret_cast<const float4*>(offp + l * 8);
      const float4 ofB = *reinterpret_cast<const float4*>(offp + l * 8 + 4);
      const u16* vf = vproj + ((long long)(cam * kNK + LSI[l])) * 256 + h * 32 + d4 * 4;

      const float ox[4] = {ofA.x, ofA.z, ofB.x, ofB.z};
      const float oy[4] = {ofA.y, ofA.w, ofB.y, ofB.w};
      const float wr[4] = {aw4.x, aw4.y, aw4.z, aw4.w};

#pragma unroll
      for (int r = 0; r < 4; ++r) {
        const float x = fmaf(rx[r], Wf, ox[r]) - 0.5f;
        const float y = fmaf(ry[r], Hf, oy[r]) - 0.5f;
        const float x0 = floorf(x);
        const float y0 = floorf(y);
        const float lx = x - x0;
        const float ly = y - y0;
        const int ix = (int)x0;
        const int iy = (int)y0;
        const int ix0 = min(max(ix, 0), Wl - 1);
        const int ix1 = min(max(ix + 1, 0), Wl - 1);
        const int iy0 = min(max(iy, 0), Hl - 1);
        const int iy1 = min(max(iy + 1, 0), Hl - 1);
        const bool bx0 = (ix >= 0) & (ix < Wl);
        const bool bx1 = (ix >= -1) & (ix + 1 < Wl);
        const bool by0 = (iy >= 0) & (iy < Hl);
        const bool by1 = (iy >= -1) & (iy + 1 < Hl);
        const float w = wr[r];
        const float wy0 = w * (1.f - ly);
        const float wy1 = w * ly;
        const float w00 = (by0 && bx0) ? wy0 * (1.f - lx) : 0.f;
        const float w01 = (by0 && bx1) ? wy0 * lx : 0.f;
        const float w10 = (by1 && bx0) ? wy1 * (1.f - lx) : 0.f;
        const float w11 = (by1 && bx1) ? wy1 * lx : 0.f;
        const ushort4 v00 = *reinterpret_cast<const ushort4*>(vf + (iy0 * Wl + ix0) * 256);
        const ushort4 v01 = *reinterpret_cast<const ushort4*>(vf + (iy0 * Wl + ix1) * 256);
        const ushort4 v10 = *reinterpret_cast<const ushort4*>(vf + (iy1 * Wl + ix0) * 256);
        const ushort4 v11 = *reinterpret_cast<const ushort4*>(vf + (iy1 * Wl + ix1) * 256);
        acc4.x = fmaf(w00, b2f(v00.x), fmaf(w01, b2f(v01.x), fmaf(w10, b2f(v10.x), fmaf(w11, b2f(v11.x), acc4.x))));
        acc4.y = fmaf(w00, b2f(v00.y), fmaf(w01, b2f(v01.y), fmaf(w10, b2f(v10.y), fmaf(w11, b2f(v11.y), acc4.y))));
        acc4.z = fmaf(w00, b2f(v00.z), fmaf(w01, b2f(v01.z), fmaf(w10, b2f(v10.z), fmaf(w11, b2f(v11.z), acc4.z))));
        acc4.w = fmaf(w00, b2f(v00.w), fmaf(w01, b2f(v01.w), fmaf(w10, b2f(v10.w), fmaf(w11, b2f(v11.w), acc4.w))));
      }
    }
  }

  const float inv = count > 0.f ? (1.f / count) : 0.f;
  ushort4 o;
  o.x = f2b(acc4.x * inv);
  o.y = f2b(acc4.y * inv);
  o.z = f2b(acc4.z * inv);
  o.w = f2b(acc4.w * inv);
  *reinterpret_cast<ushort4*>(pre + (long long)nq * kC + h * 32 + d4 * 4) = o;
  if (lane == 0) cflag[nq] = count > 0.f ? 1.f : 0.f;
}

}  // namespace

extern "C" void kernel_launch(void* const* d_in, const int* in_sizes, int n_in,
                              void* d_out, int out_size, void* d_ws, size_t ws_size,
                              hipStream_t stream) {
  (void)in_sizes; (void)n_in; (void)out_size; (void)ws_size;
  const float* query     = (const float*)d_in[0];
  const float* query_pos = (const float*)d_in[1];
  const float* value     = (const float*)d_in[2];
  const float* refpts    = (const float*)d_in[3];
  const float* l2i       = (const float*)d_in[4];
  const float* img_shape = (const float*)d_in[5];
  const float* W_val  = (const float*)d_in[8];
  const float* b_val  = (const float*)d_in[9];
  const float* W_samp = (const float*)d_in[10];
  const float* b_samp = (const float*)d_in[11];
  const float* W_attn = (const float*)d_in[12];
  const float* b_attn = (const float*)d_in[13];
  const float* W_dout = (const float*)d_in[14];
  const float* b_dout = (const float*)d_in[15];
  const float* W_out  = (const float*)d_in[16];
  const float* b_out  = (const float*)d_in[17];

  // workspace layout (bytes, 16B-aligned)
  char* p = (char*)d_ws;
  float* offaw  = (float*)p;  p += 15360000;   // [10000][384] f32 (off | aw)
  float* refcam = (float*)p;  p += 1920000;    // [6*10000][8] f32
  float* valid  = (float*)p;  p += 240000;     // [6*10000] f32
  float* cflag  = (float*)p;  p += 40000;      // [10000] f32
  u16*   vproj  = (u16*)p;    p += 41779200;   // [6*13600][256] bf16
  u16*   pre    = (u16*)p;    p += 5120000;    // [10000][256] bf16
  u16*   slots  = (u16*)p;    p += 5120000;    // [10000][256] bf16
  u16*   qpq    = (u16*)p;    p += 5120000;    // [10000][256] bf16
  u16*   WtVal  = (u16*)p;    p += 131072;     // [256][256] bf16
  u16*   WtSA   = (u16*)p;    p += 196608;     // [384][256] bf16 (samp|attn)
  u16*   WtDout = (u16*)p;    p += 131072;
  u16*   WtOut  = (u16*)p;    p += 131072;
  float* out    = (float*)d_out;

  // weight transposes (1 launch)
  k_cvt_w_all<<<dim3(36, 8), 256, 0, stream>>>(W_val, W_samp, W_attn, W_dout, W_out,
                                               WtVal, WtSA, WtDout, WtOut);

  // q + q_pos -> bf16
  k_cvt_add<<<dim3(1250), 256, 0, stream>>>(query, query_pos, qpq);

  // camera projection + visibility
  k_proj_ref<<<dim3((kCams * kNQ + 255) / 256), 256, 0, stream>>>(refpts, l2i,
                                                                  img_shape, refcam,
                                                                  valid);

  // combined sampling-offset + attention-logit projection -> offaw [10000][384]
  k_mfma<false, false><<<dim3(79, 3), 256, 0, stream>>>(
      qpq, WtSA, b_samp, b_attn, 256, nullptr, nullptr, offaw, kNQ, 384);
  k_softmax16<<<dim3(kNQ), 128, 0, stream>>>(offaw);

  // value projection with fused f32->bf16 staging -> vproj [cam][n][256]
  k_mfma_vproj<<<dim3(638, 2), 256, 0, stream>>>(value, WtVal, b_val, vproj);

  // bilinear sampling + fused masked camera-mean -> pre, cflag
  k_sample<<<dim3(kNQ / 4), 256, 0, stream>>>(vproj, refcam, offaw, valid, pre, cflag);

  // dout projection on camera-averaged features (bias scaled by cflag)
  k_mfma<true, false><<<dim3(79, 2), 256, 0, stream>>>(
      pre, WtDout, b_dout, nullptr, 0, cflag, nullptr, slots, kNQ, 256);

  // final projection + residual
  k_mfma<false, true><<<dim3(79, 2), 256, 0, stream>>>(
      slots, WtOut, b_out, nullptr, 0, nullptr, query, out, kNQ, 256);
}

// Round 5
// 147.100 us; speedup vs baseline: 7.2923x; 1.0315x over previous
//
#include <hip/hip_runtime.h>
#include <hip/hip_bf16.h>

namespace {

typedef unsigned short u16;
typedef unsigned int u32;
typedef __attribute__((ext_vector_type(8))) short bf16x8;
typedef __attribute__((ext_vector_type(4))) float f32x4;

constexpr int kNQ   = 10000;
constexpr int kCams = 6;
constexpr int kC    = 256;
constexpr int kNK   = 13600;
constexpr float kEps = 1e-5f;

__device__ __forceinline__ u16 f2b(float f) {
  union { __hip_bfloat16 h; u16 u; } cv;
  cv.h = __float2bfloat16(f);   // hardware cvt, RNE
  return cv.u;
}
__device__ __forceinline__ float b2f(u16 b) {
  return __uint_as_float(((u32)b) << 16);
}
__device__ __forceinline__ bf16x8 pack8(const float4& a, const float4& b) {
  bf16x8 v;
  v[0] = (short)f2b(a.x); v[1] = (short)f2b(a.y);
  v[2] = (short)f2b(a.z); v[3] = (short)f2b(a.w);
  v[4] = (short)f2b(b.x); v[5] = (short)f2b(b.y);
  v[6] = (short)f2b(b.z); v[7] = (short)f2b(b.w);
  return v;
}

// ---------------------------------------------------------------------------
// All 5 weight transposes in one launch. bn-blocks: [0,8)=val [8,16)=samp
// [16,20)=attn(->rows 256..383 of samp-attn buffer) [20,28)=dout [28,36)=out
// ---------------------------------------------------------------------------
__global__ __launch_bounds__(256) void k_cvt_w_all(
    const float* __restrict__ w_val, const float* __restrict__ w_samp,
    const float* __restrict__ w_attn, const float* __restrict__ w_dout,
    const float* __restrict__ w_out, u16* __restrict__ t_val,
    u16* __restrict__ t_sa, u16* __restrict__ t_dout, u16* __restrict__ t_out) {
  __shared__ float t[32][33];
  const int bn = blockIdx.x;
  const int bk = blockIdx.y;
  const int tid = threadIdx.x;
  const float* W; u16* Wt; int N, lb;
  if (bn < 8)       { W = w_val;  Wt = t_val;            N = 256; lb = bn; }
  else if (bn < 16) { W = w_samp; Wt = t_sa;             N = 256; lb = bn - 8; }
  else if (bn < 20) { W = w_attn; Wt = t_sa + 256 * 256; N = 128; lb = bn - 16; }
  else if (bn < 28) { W = w_dout; Wt = t_dout;           N = 256; lb = bn - 20; }
  else              { W = w_out;  Wt = t_out;            N = 256; lb = bn - 28; }
#pragma unroll
  for (int e = 0; e < 4; ++e) {
    const int i = e * 256 + tid;
    const int kk = i >> 5, nn = i & 31;
    t[kk][nn] = W[(bk * 32 + kk) * N + lb * 32 + nn];
  }
  __syncthreads();
#pragma unroll
  for (int e = 0; e < 4; ++e) {
    const int i = e * 256 + tid;
    const int nn = i >> 5, kk = i & 31;
    Wt[(lb * 32 + nn) * 256 + bk * 32 + kk] = f2b(t[kk][nn]);
  }
}

// ---------------------------------------------------------------------------
// qpq[i] = bf16(a[i] + b[i]); 8 elems/thread
// ---------------------------------------------------------------------------
__global__ __launch_bounds__(256) void k_cvt_add(const float* __restrict__ a,
                                                 const float* __restrict__ b,
                                                 u16* __restrict__ out) {
  const int t = blockIdx.x * 256 + threadIdx.x;
  const int i = t * 8;
  const float4 x0 = *reinterpret_cast<const float4*>(a + i);
  const float4 x1 = *reinterpret_cast<const float4*>(a + i + 4);
  const float4 y0 = *reinterpret_cast<const float4*>(b + i);
  const float4 y1 = *reinterpret_cast<const float4*>(b + i + 4);
  float4 s0, s1;
  s0.x = x0.x + y0.x; s0.y = x0.y + y0.y; s0.z = x0.z + y0.z; s0.w = x0.w + y0.w;
  s1.x = x1.x + y1.x; s1.y = x1.y + y1.y; s1.z = x1.z + y1.z; s1.w = x1.w + y1.w;
  *reinterpret_cast<bf16x8*>(out + i) = pack8(s0, s1);
}

// ---------------------------------------------------------------------------
// MFMA GEMM, depth-1 register-prefetch pipeline (T14 async-stage split):
// out[M][Ntot] = A_bf16[M][256] @ Wt_bf16[Ntot][256]^T + bias (+ addend f32).
// Tile 128x128xK64, 4 waves, XOR-swizzled LDS. Split bias, per-row bias scale.
// ---------------------------------------------------------------------------
template <bool OUT_BF16, bool HAS_ADD>
__global__ __launch_bounds__(256) void k_mfma(const u16* __restrict__ A,
                                              const u16* __restrict__ Wt,
                                              const float* __restrict__ bias,
                                              const float* __restrict__ bias2,
                                              int nsplit,
                                              const float* __restrict__ bias_scale,
                                              const float* __restrict__ addend,
                                              void* __restrict__ outp,
                                              int M, int Ntot) {
  __shared__ u16 As[128 * 64];
  __shared__ u16 Bs[128 * 64];
  const int tid = threadIdx.x;
  const int m0 = blockIdx.x * 128;
  const int n0 = blockIdx.y * 128;
  const int wave = tid >> 6;
  const int lane = tid & 63;
  const int wr = wave >> 1;
  const int wc = wave & 1;
  const int lr = lane & 15;
  const int lg = lane >> 4;
  const int srow = tid >> 3;   // 0..31
  const int slot = tid & 7;

  const u16* aptr[4];
  const u16* bptr[4];
  int soff[4];
#pragma unroll
  for (int c = 0; c < 4; ++c) {
    const int rowA = c * 32 + srow;
    const int ra = min(m0 + rowA, M - 1);
    aptr[c] = A + (long long)ra * 256 + slot * 8;
    bptr[c] = Wt + (long long)(n0 + rowA) * 256 + slot * 8;
    soff[c] = rowA * 64 + ((slot ^ (rowA & 7)) << 3);
  }

  f32x4 acc[4][4] = {};

  bf16x8 ca[4], cb[4];
#pragma unroll
  for (int c = 0; c < 4; ++c) {
    ca[c] = *reinterpret_cast<const bf16x8*>(aptr[c]);
    cb[c] = *reinterpret_cast<const bf16x8*>(bptr[c]);
  }

#pragma unroll
  for (int kt = 0; kt < 4; ++kt) {
    bf16x8 na[4], nb[4];
    if (kt < 3) {
      const int k1 = (kt + 1) * 64;
#pragma unroll
      for (int c = 0; c < 4; ++c) {
        na[c] = *reinterpret_cast<const bf16x8*>(aptr[c] + k1);
        nb[c] = *reinterpret_cast<const bf16x8*>(bptr[c] + k1);
      }
    }
#pragma unroll
    for (int c = 0; c < 4; ++c) {
      *reinterpret_cast<bf16x8*>(&As[soff[c]]) = ca[c];
      *reinterpret_cast<bf16x8*>(&Bs[soff[c]]) = cb[c];
    }
    __syncthreads();
#pragma unroll
    for (int ks = 0; ks < 2; ++ks) {
      bf16x8 af[4], bfr[4];
#pragma unroll
      for (int mi = 0; mi < 4; ++mi) {
        const int r = wr * 64 + mi * 16 + lr;
        const int s = ks * 4 + lg;
        af[mi] = *reinterpret_cast<const bf16x8*>(&As[r * 64 + ((s ^ (r & 7)) << 3)]);
      }
#pragma unroll
      for (int ni = 0; ni < 4; ++ni) {
        const int r = wc * 64 + ni * 16 + lr;
        const int s = ks * 4 + lg;
        bfr[ni] = *reinterpret_cast<const bf16x8*>(&Bs[r * 64 + ((s ^ (r & 7)) << 3)]);
      }
#pragma unroll
      for (int mi = 0; mi < 4; ++mi)
#pragma unroll
        for (int ni = 0; ni < 4; ++ni)
          acc[mi][ni] = __builtin_amdgcn_mfma_f32_16x16x32_bf16(af[mi], bfr[ni],
                                                                acc[mi][ni], 0, 0, 0);
    }
    if (kt < 3) {
      __syncthreads();
#pragma unroll
      for (int c = 0; c < 4; ++c) { ca[c] = na[c]; cb[c] = nb[c]; }
    }
  }

#pragma unroll
  for (int mi = 0; mi < 4; ++mi) {
#pragma unroll
    for (int reg = 0; reg < 4; ++reg) {
      const int row = m0 + wr * 64 + mi * 16 + lg * 4 + reg;
      if (row < M) {
        const float bs = bias_scale ? bias_scale[row] : 1.f;
#pragma unroll
        for (int ni = 0; ni < 4; ++ni) {
          const int col = n0 + wc * 64 + ni * 16 + lr;
          const float b = (bias2 && col >= nsplit) ? bias2[col - nsplit] : bias[col];
          float v = acc[mi][ni][reg] + b * bs;
          if (HAS_ADD) v += addend[(long long)row * Ntot + col];
          if (OUT_BF16)
            ((u16*)outp)[(long long)row * Ntot + col] = f2b(v);
          else
            ((float*)outp)[(long long)row * Ntot + col] = v;
        }
      }
    }
  }
}

// ---------------------------------------------------------------------------
// Value-projection MFMA GEMM, same pipeline; A staged from f32 with fused
// bf16 convert at ds_write time and [n][cam]->row remap (row = cam*kNK+n).
// ---------------------------------------------------------------------------
__global__ __launch_bounds__(256) void k_mfma_vproj(const float* __restrict__ value,
                                                    const u16* __restrict__ Wt,
                                                    const float* __restrict__ bias,
                                                    u16* __restrict__ outp) {
  constexpr int M = kNK * kCams;
  __shared__ u16 As[128 * 64];
  __shared__ u16 Bs[128 * 64];
  const int tid = threadIdx.x;
  const int m0 = blockIdx.x * 128;
  const int n0 = blockIdx.y * 128;
  const int wave = tid >> 6;
  const int lane = tid & 63;
  const int wr = wave >> 1;
  const int wc = wave & 1;
  const int lr = lane & 15;
  const int lg = lane >> 4;
  const int srow = tid >> 3;
  const int slot = tid & 7;

  const float* aptr[4];
  const u16* bptr[4];
  int soff[4];
#pragma unroll
  for (int c = 0; c < 4; ++c) {
    const int rowA = c * 32 + srow;
    const int g = min(m0 + rowA, M - 1);
    const int cam = g / kNK;
    const int n = g - cam * kNK;
    aptr[c] = value + (long long)(n * kCams + cam) * 256 + slot * 8;
    bptr[c] = Wt + (long long)(n0 + rowA) * 256 + slot * 8;
    soff[c] = rowA * 64 + ((slot ^ (rowA & 7)) << 3);
  }

  f32x4 acc[4][4] = {};

  float4 caf[8];
  bf16x8 cb[4];
#pragma unroll
  for (int c = 0; c < 4; ++c) {
    caf[2 * c]     = *reinterpret_cast<const float4*>(aptr[c]);
    caf[2 * c + 1] = *reinterpret_cast<const float4*>(aptr[c] + 4);
    cb[c] = *reinterpret_cast<const bf16x8*>(bptr[c]);
  }

#pragma unroll
  for (int kt = 0; kt < 4; ++kt) {
    float4 naf[8];
    bf16x8 nb[4];
    if (kt < 3) {
      const int k1 = (kt + 1) * 64;
#pragma unroll
      for (int c = 0; c < 4; ++c) {
        naf[2 * c]     = *reinterpret_cast<const float4*>(aptr[c] + k1);
        naf[2 * c + 1] = *reinterpret_cast<const float4*>(aptr[c] + k1 + 4);
        nb[c] = *reinterpret_cast<const bf16x8*>(bptr[c] + k1 * 2 / 2);
      }
    }
#pragma unroll
    for (int c = 0; c < 4; ++c) {
      *reinterpret_cast<bf16x8*>(&As[soff[c]]) = pack8(caf[2 * c], caf[2 * c + 1]);
      *reinterpret_cast<bf16x8*>(&Bs[soff[c]]) = cb[c];
    }
    __syncthreads();
#pragma unroll
    for (int ks = 0; ks < 2; ++ks) {
      bf16x8 af[4], bfr[4];
#pragma unroll
      for (int mi = 0; mi < 4; ++mi) {
        const int r = wr * 64 + mi * 16 + lr;
        const int s = ks * 4 + lg;
        af[mi] = *reinterpret_cast<const bf16x8*>(&As[r * 64 + ((s ^ (r & 7)) << 3)]);
      }
#pragma unroll
      for (int ni = 0; ni < 4; ++ni) {
        const int r = wc * 64 + ni * 16 + lr;
        const int s = ks * 4 + lg;
        bfr[ni] = *reinterpret_cast<const bf16x8*>(&Bs[r * 64 + ((s ^ (r & 7)) << 3)]);
      }
#pragma unroll
      for (int mi = 0; mi < 4; ++mi)
#pragma unroll
        for (int ni = 0; ni < 4; ++ni)
          acc[mi][ni] = __builtin_amdgcn_mfma_f32_16x16x32_bf16(af[mi], bfr[ni],
                                                                acc[mi][ni], 0, 0, 0);
    }
    if (kt < 3) {
      __syncthreads();
#pragma unroll
      for (int c = 0; c < 4; ++c) {
        caf[2 * c] = naf[2 * c];
        caf[2 * c + 1] = naf[2 * c + 1];
        cb[c] = nb[c];
      }
    }
  }

#pragma unroll
  for (int mi = 0; mi < 4; ++mi) {
#pragma unroll
    for (int reg = 0; reg < 4; ++reg) {
      const int row = m0 + wr * 64 + mi * 16 + lg * 4 + reg;
      if (row < M) {
#pragma unroll
        for (int ni = 0; ni < 4; ++ni) {
          const int col = n0 + wc * 64 + ni * 16 + lr;
          outp[(long long)row * 256 + col] = f2b(acc[mi][ni][reg] + bias[col]);
        }
      }
    }
  }
}

// ---------------------------------------------------------------------------
// Softmax over each 16-wide group; logits live at offaw[nq*384 + 256 + t].
// ---------------------------------------------------------------------------
__global__ __launch_bounds__(128) void k_softmax16(float* __restrict__ offaw) {
  const int nq = blockIdx.x;
  const int t = threadIdx.x;
  float* p = offaw + (long long)nq * 384 + 256 + t;
  float v = *p;
  float mx = v;
#pragma unroll
  for (int s = 1; s < 16; s <<= 1) mx = fmaxf(mx, __shfl_xor(mx, s));
  const float e = expf(v - mx);
  float sm = e;
#pragma unroll
  for (int s = 1; s < 16; s <<= 1) sm += __shfl_xor(sm, s);
  *p = e / sm;
}

// ---------------------------------------------------------------------------
// Camera projection of reference points + visibility mask.
// ---------------------------------------------------------------------------
__global__ __launch_bounds__(256) void k_proj_ref(const float* __restrict__ refpts,
                                                  const float* __restrict__ l2i,
                                                  const float* __restrict__ img_shape,
                                                  float* __restrict__ refcam,
                                                  float* __restrict__ valid) {
  const int idx = blockIdx.x * blockDim.x + threadIdx.x;
  if (idx >= kCams * kNQ) return;
  const int cam = idx / kNQ;
  const int nq = idx - cam * kNQ;
  const float* Mp = l2i + cam * 12;
  float m[12];
#pragma unroll
  for (int i = 0; i < 12; ++i) m[i] = Mp[i];
  const float ih = img_shape[cam * 2 + 0];
  const float iw = img_shape[cam * 2 + 1];
  float anyv = 0.f;
  float* rcout = refcam + (long long)idx * 8;
#pragma unroll
  for (int r = 0; r < 4; ++r) {
    const float* rp = refpts + ((long long)nq * 4 + r) * 3;
    const float X = rp[0] * 102.4f + (-51.2f);
    const float Y = rp[1] * 102.4f + (-51.2f);
    const float Z = rp[2] * 8.0f + (-5.0f);
    const float cx = m[0] * X + m[1] * Y + m[2] * Z + m[3];
    const float cy = m[4] * X + m[5] * Y + m[6] * Z + m[7];
    const float cz = m[8] * X + m[9] * Y + m[10] * Z + m[11];
    const float zc = fmaxf(cz, kEps);
    const float xn = cx / zc / iw;
    const float yn = cy / zc / ih;
    rcout[r * 2 + 0] = xn;
    rcout[r * 2 + 1] = yn;
    if ((cz > kEps) && (xn > 0.f) && (xn < 1.f) && (yn > 0.f) && (yn < 1.f)) anyv = 1.f;
  }
  valid[idx] = anyv;
}

// ---------------------------------------------------------------------------
// Bilinear sampling with fused masked camera-mean. One wave per nq; lane =
// h*8 + d4. Loops cameras with wave-uniform valid skip; accumulates the
// camera sum in registers; writes pre[nq][256] bf16 and cflag[nq].
// ---------------------------------------------------------------------------
__global__ __launch_bounds__(256) void k_sample(const u16* __restrict__ vproj,
                                                const float* __restrict__ refcam,
                                                const float* __restrict__ offaw,
                                                const float* __restrict__ valid,
                                                u16* __restrict__ pre,
                                                float* __restrict__ cflag) {
  const int nq = blockIdx.x * 4 + (threadIdx.x >> 6);
  const int lane = threadIdx.x & 63;
  const int h = lane >> 3;
  const int d4 = lane & 7;

  static constexpr int SHH[4] = {64, 32, 16, 8};
  static constexpr int SHW[4] = {160, 80, 40, 20};
  static constexpr int LSI[4] = {0, 10240, 12800, 13440};

  const float* offp = offaw + (long long)nq * 384 + h * 32;
  const float* awp = offaw + (long long)nq * 384 + 256 + h * 16;

  float4 acc4 = {0.f, 0.f, 0.f, 0.f};
  float count = 0.f;

  for (int cam = 0; cam < kCams; ++cam) {
    const float vl = valid[cam * kNQ + nq];
    if (vl == 0.f) continue;  // wave-uniform skip
    count += 1.f;

    const float* rcp = refcam + (long long)(cam * kNQ + nq) * 8;
    const float4 rcA = *reinterpret_cast<const float4*>(rcp);
    const float4 rcB = *reinterpret_cast<const float4*>(rcp + 4);
    const float rx[4] = {rcA.x, rcA.z, rcB.x, rcB.z};
    const float ry[4] = {rcA.y, rcA.w, rcB.y, rcB.w};

#pragma unroll
    for (int l = 0; l < 4; ++l) {
      const int Hl = SHH[l];
      const int Wl = SHW[l];
      const float Hf = (float)Hl;
      const float Wf = (float)Wl;
      const float4 aw4 = *reinterpret_cast<const float4*>(awp + l * 4);
      const float4 ofA = *reinterpret_cast<const float4*>(offp + l * 8);
      const float4 ofB = *reinterpret_cast<const float4*>(offp + l * 8 + 4);
      const u16* vf = vproj + ((long long)(cam * kNK + LSI[l])) * 256 + h * 32 + d4 * 4;

      const float ox[4] = {ofA.x, ofA.z, ofB.x, ofB.z};
      const float oy[4] = {ofA.y, ofA.w, ofB.y, ofB.w};
      const float wr[4] = {aw4.x, aw4.y, aw4.z, aw4.w};

#pragma unroll
      for (int r = 0; r < 4; ++r) {
        const float x = fmaf(rx[r], Wf, ox[r]) - 0.5f;
        const float y = fmaf(ry[r], Hf, oy[r]) - 0.5f;
        const float x0 = floorf(x);
        const float y0 = floorf(y);
        const float lx = x - x0;
        const float ly = y - y0;
        const int ix = (int)x0;
        const int iy = (int)y0;
        const int ix0 = min(max(ix, 0), Wl - 1);
        const int ix1 = min(max(ix + 1, 0), Wl - 1);
        const int iy0 = min(max(iy, 0), Hl - 1);
        const int iy1 = min(max(iy + 1, 0), Hl - 1);
        const bool bx0 = (ix >= 0) & (ix < Wl);
        const bool bx1 = (ix >= -1) & (ix + 1 < Wl);
        const bool by0 = (iy >= 0) & (iy < Hl);
        const bool by1 = (iy >= -1) & (iy + 1 < Hl);
        const float w = wr[r];
        const float wy0 = w * (1.f - ly);
        const float wy1 = w * ly;
        const float w00 = (by0 && bx0) ? wy0 * (1.f - lx) : 0.f;
        const float w01 = (by0 && bx1) ? wy0 * lx : 0.f;
        const float w10 = (by1 && bx0) ? wy1 * (1.f - lx) : 0.f;
        const float w11 = (by1 && bx1) ? wy1 * lx : 0.f;
        const ushort4 v00 = *reinterpret_cast<const ushort4*>(vf + (iy0 * Wl + ix0) * 256);
        const ushort4 v01 = *reinterpret_cast<const ushort4*>(vf + (iy0 * Wl + ix1) * 256);
        const ushort4 v10 = *reinterpret_cast<const ushort4*>(vf + (iy1 * Wl + ix0) * 256);
        const ushort4 v11 = *reinterpret_cast<const ushort4*>(vf + (iy1 * Wl + ix1) * 256);
        acc4.x = fmaf(w00, b2f(v00.x), fmaf(w01, b2f(v01.x), fmaf(w10, b2f(v10.x), fmaf(w11, b2f(v11.x), acc4.x))));
        acc4.y = fmaf(w00, b2f(v00.y), fmaf(w01, b2f(v01.y), fmaf(w10, b2f(v10.y), fmaf(w11, b2f(v11.y), acc4.y))));
        acc4.z = fmaf(w00, b2f(v00.z), fmaf(w01, b2f(v01.z), fmaf(w10, b2f(v10.z), fmaf(w11, b2f(v11.z), acc4.z))));
        acc4.w = fmaf(w00, b2f(v00.w), fmaf(w01, b2f(v01.w), fmaf(w10, b2f(v10.w), fmaf(w11, b2f(v11.w), acc4.w))));
      }
    }
  }

  const float inv = count > 0.f ? (1.f / count) : 0.f;
  ushort4 o;
  o.x = f2b(acc4.x * inv);
  o.y = f2b(acc4.y * inv);
  o.z = f2b(acc4.z * inv);
  o.w = f2b(acc4.w * inv);
  *reinterpret_cast<ushort4*>(pre + (long long)nq * kC + h * 32 + d4 * 4) = o;
  if (lane == 0) cflag[nq] = count > 0.f ? 1.f : 0.f;
}

}  // namespace

extern "C" void kernel_launch(void* const* d_in, const int* in_sizes, int n_in,
                              void* d_out, int out_size, void* d_ws, size_t ws_size,
                              hipStream_t stream) {
  (void)in_sizes; (void)n_in; (void)out_size; (void)ws_size;
  const float* query     = (const float*)d_in[0];
  const float* query_pos = (const float*)d_in[1];
  const float* value     = (const float*)d_in[2];
  const float* refpts    = (const float*)d_in[3];
  const float* l2i       = (const float*)d_in[4];
  const float* img_shape = (const float*)d_in[5];
  const float* W_val  = (const float*)d_in[8];
  const float* b_val  = (const float*)d_in[9];
  const float* W_samp = (const float*)d_in[10];
  const float* b_samp = (const float*)d_in[11];
  const float* W_attn = (const float*)d_in[12];
  const float* b_attn = (const float*)d_in[13];
  const float* W_dout = (const float*)d_in[14];
  const float* b_dout = (const float*)d_in[15];
  const float* W_out  = (const float*)d_in[16];
  const float* b_out  = (const float*)d_in[17];

  // workspace layout (bytes, 16B-aligned)
  char* p = (char*)d_ws;
  float* offaw  = (float*)p;  p += 15360000;   // [10000][384] f32 (off | aw)
  float* refcam = (float*)p;  p += 1920000;    // [6*10000][8] f32
  float* valid  = (float*)p;  p += 240000;     // [6*10000] f32
  float* cflag  = (float*)p;  p += 40000;      // [10000] f32
  u16*   vproj  = (u16*)p;    p += 41779200;   // [6*13600][256] bf16
  u16*   pre    = (u16*)p;    p += 5120000;    // [10000][256] bf16
  u16*   slots  = (u16*)p;    p += 5120000;    // [10000][256] bf16
  u16*   qpq    = (u16*)p;    p += 5120000;    // [10000][256] bf16
  u16*   WtVal  = (u16*)p;    p += 131072;     // [256][256] bf16
  u16*   WtSA   = (u16*)p;    p += 196608;     // [384][256] bf16 (samp|attn)
  u16*   WtDout = (u16*)p;    p += 131072;
  u16*   WtOut  = (u16*)p;    p += 131072;
  float* out    = (float*)d_out;

  // weight transposes (1 launch)
  k_cvt_w_all<<<dim3(36, 8), 256, 0, stream>>>(W_val, W_samp, W_attn, W_dout, W_out,
                                               WtVal, WtSA, WtDout, WtOut);

  // q + q_pos -> bf16
  k_cvt_add<<<dim3(1250), 256, 0, stream>>>(query, query_pos, qpq);

  // camera projection + visibility
  k_proj_ref<<<dim3((kCams * kNQ + 255) / 256), 256, 0, stream>>>(refpts, l2i,
                                                                  img_shape, refcam,
                                                                  valid);

  // combined sampling-offset + attention-logit projection -> offaw [10000][384]
  k_mfma<false, false><<<dim3(79, 3), 256, 0, stream>>>(
      qpq, WtSA, b_samp, b_attn, 256, nullptr, nullptr, offaw, kNQ, 384);
  k_softmax16<<<dim3(kNQ), 128, 0, stream>>>(offaw);

  // value projection with fused f32->bf16 staging -> vproj [cam][n][256]
  k_mfma_vproj<<<dim3(638, 2), 256, 0, stream>>>(value, WtVal, b_val, vproj);

  // bilinear sampling + fused masked camera-mean -> pre, cflag
  k_sample<<<dim3(kNQ / 4), 256, 0, stream>>>(vproj, refcam, offaw, valid, pre, cflag);

  // dout projection on camera-averaged features (bias scaled by cflag)
  k_mfma<true, false><<<dim3(79, 2), 256, 0, stream>>>(
      pre, WtDout, b_dout, nullptr, 0, cflag, nullptr, slots, kNQ, 256);

  // final projection + residual
  k_mfma<false, true><<<dim3(79, 2), 256, 0, stream>>>(
      slots, WtOut, b_out, nullptr, 0, nullptr, query, out, kNQ, 256);
}

// Round 6
// 132.038 us; speedup vs baseline: 8.1241x; 1.1141x over previous
//
#include <hip/hip_runtime.h>
#include <hip/hip_bf16.h>

namespace {

typedef unsigned short u16;
typedef unsigned int u32;
typedef unsigned char u8;
typedef __attribute__((ext_vector_type(8))) short bf16x8;
typedef __attribute__((ext_vector_type(4))) float f32x4;
typedef __attribute__((ext_vector_type(2))) float f32x2;

constexpr int kNQ   = 10000;
constexpr int kCams = 6;
constexpr int kC    = 256;
constexpr int kNK   = 13600;
constexpr float kEps = 1e-5f;

__device__ __forceinline__ u16 f2b(float f) {
  union { __hip_bfloat16 h; u16 u; } cv;
  cv.h = __float2bfloat16(f);   // hardware cvt, RNE
  return cv.u;
}
__device__ __forceinline__ float b2f(u16 b) {
  return __uint_as_float(((u32)b) << 16);
}
__device__ __forceinline__ bf16x8 pack8(const float4& a, const float4& b) {
  bf16x8 v;
  v[0] = (short)f2b(a.x); v[1] = (short)f2b(a.y);
  v[2] = (short)f2b(a.z); v[3] = (short)f2b(a.w);
  v[4] = (short)f2b(b.x); v[5] = (short)f2b(b.y);
  v[6] = (short)f2b(b.z); v[7] = (short)f2b(b.w);
  return v;
}
__device__ __forceinline__ u8 f2fp8(float v) {
  const u32 t = __builtin_amdgcn_cvt_pk_fp8_f32(v, 0.f, 0u, false);
  return (u8)(t & 0xffu);
}

// ---------------------------------------------------------------------------
// All 5 weight transposes in one launch. bn-blocks: [0,8)=val [8,16)=samp
// [16,20)=attn(->rows 256..383 of samp-attn buffer) [20,28)=dout [28,36)=out
// ---------------------------------------------------------------------------
__global__ __launch_bounds__(256) void k_cvt_w_all(
    const float* __restrict__ w_val, const float* __restrict__ w_samp,
    const float* __restrict__ w_attn, const float* __restrict__ w_dout,
    const float* __restrict__ w_out, u16* __restrict__ t_val,
    u16* __restrict__ t_sa, u16* __restrict__ t_dout, u16* __restrict__ t_out) {
  __shared__ float t[32][33];
  const int bn = blockIdx.x;
  const int bk = blockIdx.y;
  const int tid = threadIdx.x;
  const float* W; u16* Wt; int N, lb;
  if (bn < 8)       { W = w_val;  Wt = t_val;            N = 256; lb = bn; }
  else if (bn < 16) { W = w_samp; Wt = t_sa;             N = 256; lb = bn - 8; }
  else if (bn < 20) { W = w_attn; Wt = t_sa + 256 * 256; N = 128; lb = bn - 16; }
  else if (bn < 28) { W = w_dout; Wt = t_dout;           N = 256; lb = bn - 20; }
  else              { W = w_out;  Wt = t_out;            N = 256; lb = bn - 28; }
#pragma unroll
  for (int e = 0; e < 4; ++e) {
    const int i = e * 256 + tid;
    const int kk = i >> 5, nn = i & 31;
    t[kk][nn] = W[(bk * 32 + kk) * N + lb * 32 + nn];
  }
  __syncthreads();
#pragma unroll
  for (int e = 0; e < 4; ++e) {
    const int i = e * 256 + tid;
    const int nn = i >> 5, kk = i & 31;
    Wt[(lb * 32 + nn) * 256 + bk * 32 + kk] = f2b(t[kk][nn]);
  }
}

// ---------------------------------------------------------------------------
// qpq[i] = bf16(a[i] + b[i]); 8 elems/thread
// ---------------------------------------------------------------------------
__global__ __launch_bounds__(256) void k_cvt_add(const float* __restrict__ a,
                                                 const float* __restrict__ b,
                                                 u16* __restrict__ out) {
  const int t = blockIdx.x * 256 + threadIdx.x;
  const int i = t * 8;
  const float4 x0 = *reinterpret_cast<const float4*>(a + i);
  const float4 x1 = *reinterpret_cast<const float4*>(a + i + 4);
  const float4 y0 = *reinterpret_cast<const float4*>(b + i);
  const float4 y1 = *reinterpret_cast<const float4*>(b + i + 4);
  float4 s0, s1;
  s0.x = x0.x + y0.x; s0.y = x0.y + y0.y; s0.z = x0.z + y0.z; s0.w = x0.w + y0.w;
  s1.x = x1.x + y1.x; s1.y = x1.y + y1.y; s1.z = x1.z + y1.z; s1.w = x1.w + y1.w;
  *reinterpret_cast<bf16x8*>(out + i) = pack8(s0, s1);
}

// ---------------------------------------------------------------------------
// MFMA GEMM, depth-1 register-prefetch pipeline:
// out[M][Ntot] = A_bf16[M][256] @ Wt_bf16[Ntot][256]^T + bias (+ addend f32).
// Tile 128x128xK64, 4 waves, XOR-swizzled LDS. Split bias, per-row bias scale.
// ---------------------------------------------------------------------------
template <bool OUT_BF16, bool HAS_ADD>
__global__ __launch_bounds__(256) void k_mfma(const u16* __restrict__ A,
                                              const u16* __restrict__ Wt,
                                              const float* __restrict__ bias,
                                              const float* __restrict__ bias2,
                                              int nsplit,
                                              const float* __restrict__ bias_scale,
                                              const float* __restrict__ addend,
                                              void* __restrict__ outp,
                                              int M, int Ntot) {
  __shared__ u16 As[128 * 64];
  __shared__ u16 Bs[128 * 64];
  const int tid = threadIdx.x;
  const int m0 = blockIdx.x * 128;
  const int n0 = blockIdx.y * 128;
  const int wave = tid >> 6;
  const int lane = tid & 63;
  const int wr = wave >> 1;
  const int wc = wave & 1;
  const int lr = lane & 15;
  const int lg = lane >> 4;
  const int srow = tid >> 3;   // 0..31
  const int slot = tid & 7;

  const u16* aptr[4];
  const u16* bptr[4];
  int soff[4];
#pragma unroll
  for (int c = 0; c < 4; ++c) {
    const int rowA = c * 32 + srow;
    const int ra = min(m0 + rowA, M - 1);
    aptr[c] = A + (long long)ra * 256 + slot * 8;
    bptr[c] = Wt + (long long)(n0 + rowA) * 256 + slot * 8;
    soff[c] = rowA * 64 + ((slot ^ (rowA & 7)) << 3);
  }

  f32x4 acc[4][4] = {};

  bf16x8 ca[4], cb[4];
#pragma unroll
  for (int c = 0; c < 4; ++c) {
    ca[c] = *reinterpret_cast<const bf16x8*>(aptr[c]);
    cb[c] = *reinterpret_cast<const bf16x8*>(bptr[c]);
  }

#pragma unroll
  for (int kt = 0; kt < 4; ++kt) {
    bf16x8 na[4], nb[4];
    if (kt < 3) {
      const int k1 = (kt + 1) * 64;
#pragma unroll
      for (int c = 0; c < 4; ++c) {
        na[c] = *reinterpret_cast<const bf16x8*>(aptr[c] + k1);
        nb[c] = *reinterpret_cast<const bf16x8*>(bptr[c] + k1);
      }
    }
#pragma unroll
    for (int c = 0; c < 4; ++c) {
      *reinterpret_cast<bf16x8*>(&As[soff[c]]) = ca[c];
      *reinterpret_cast<bf16x8*>(&Bs[soff[c]]) = cb[c];
    }
    __syncthreads();
#pragma unroll
    for (int ks = 0; ks < 2; ++ks) {
      bf16x8 af[4], bfr[4];
#pragma unroll
      for (int mi = 0; mi < 4; ++mi) {
        const int r = wr * 64 + mi * 16 + lr;
        const int s = ks * 4 + lg;
        af[mi] = *reinterpret_cast<const bf16x8*>(&As[r * 64 + ((s ^ (r & 7)) << 3)]);
      }
#pragma unroll
      for (int ni = 0; ni < 4; ++ni) {
        const int r = wc * 64 + ni * 16 + lr;
        const int s = ks * 4 + lg;
        bfr[ni] = *reinterpret_cast<const bf16x8*>(&Bs[r * 64 + ((s ^ (r & 7)) << 3)]);
      }
#pragma unroll
      for (int mi = 0; mi < 4; ++mi)
#pragma unroll
        for (int ni = 0; ni < 4; ++ni)
          acc[mi][ni] = __builtin_amdgcn_mfma_f32_16x16x32_bf16(af[mi], bfr[ni],
                                                                acc[mi][ni], 0, 0, 0);
    }
    if (kt < 3) {
      __syncthreads();
#pragma unroll
      for (int c = 0; c < 4; ++c) { ca[c] = na[c]; cb[c] = nb[c]; }
    }
  }

#pragma unroll
  for (int mi = 0; mi < 4; ++mi) {
#pragma unroll
    for (int reg = 0; reg < 4; ++reg) {
      const int row = m0 + wr * 64 + mi * 16 + lg * 4 + reg;
      if (row < M) {
        const float bs = bias_scale ? bias_scale[row] : 1.f;
#pragma unroll
        for (int ni = 0; ni < 4; ++ni) {
          const int col = n0 + wc * 64 + ni * 16 + lr;
          const float b = (bias2 && col >= nsplit) ? bias2[col - nsplit] : bias[col];
          float v = acc[mi][ni][reg] + b * bs;
          if (HAS_ADD) v += addend[(long long)row * Ntot + col];
          if (OUT_BF16)
            ((u16*)outp)[(long long)row * Ntot + col] = f2b(v);
          else
            ((float*)outp)[(long long)row * Ntot + col] = v;
        }
      }
    }
  }
}

// ---------------------------------------------------------------------------
// Value-projection MFMA GEMM; A staged from f32 with fused bf16 convert at
// ds_write time and [n][cam]->row remap (row = cam*kNK+n). fp8-e4m3 output.
// ---------------------------------------------------------------------------
__global__ __launch_bounds__(256) void k_mfma_vproj(const float* __restrict__ value,
                                                    const u16* __restrict__ Wt,
                                                    const float* __restrict__ bias,
                                                    u8* __restrict__ outp) {
  constexpr int M = kNK * kCams;
  __shared__ u16 As[128 * 64];
  __shared__ u16 Bs[128 * 64];
  const int tid = threadIdx.x;
  const int m0 = blockIdx.x * 128;
  const int n0 = blockIdx.y * 128;
  const int wave = tid >> 6;
  const int lane = tid & 63;
  const int wr = wave >> 1;
  const int wc = wave & 1;
  const int lr = lane & 15;
  const int lg = lane >> 4;
  const int srow = tid >> 3;
  const int slot = tid & 7;

  const float* aptr[4];
  const u16* bptr[4];
  int soff[4];
#pragma unroll
  for (int c = 0; c < 4; ++c) {
    const int rowA = c * 32 + srow;
    const int g = min(m0 + rowA, M - 1);
    const int cam = g / kNK;
    const int n = g - cam * kNK;
    aptr[c] = value + (long long)(n * kCams + cam) * 256 + slot * 8;
    bptr[c] = Wt + (long long)(n0 + rowA) * 256 + slot * 8;
    soff[c] = rowA * 64 + ((slot ^ (rowA & 7)) << 3);
  }

  f32x4 acc[4][4] = {};

  float4 caf[8];
  bf16x8 cb[4];
#pragma unroll
  for (int c = 0; c < 4; ++c) {
    caf[2 * c]     = *reinterpret_cast<const float4*>(aptr[c]);
    caf[2 * c + 1] = *reinterpret_cast<const float4*>(aptr[c] + 4);
    cb[c] = *reinterpret_cast<const bf16x8*>(bptr[c]);
  }

#pragma unroll
  for (int kt = 0; kt < 4; ++kt) {
    float4 naf[8];
    bf16x8 nb[4];
    if (kt < 3) {
      const int k1 = (kt + 1) * 64;
#pragma unroll
      for (int c = 0; c < 4; ++c) {
        naf[2 * c]     = *reinterpret_cast<const float4*>(aptr[c] + k1);
        naf[2 * c + 1] = *reinterpret_cast<const float4*>(aptr[c] + k1 + 4);
        nb[c] = *reinterpret_cast<const bf16x8*>(bptr[c] + k1);
      }
    }
#pragma unroll
    for (int c = 0; c < 4; ++c) {
      *reinterpret_cast<bf16x8*>(&As[soff[c]]) = pack8(caf[2 * c], caf[2 * c + 1]);
      *reinterpret_cast<bf16x8*>(&Bs[soff[c]]) = cb[c];
    }
    __syncthreads();
#pragma unroll
    for (int ks = 0; ks < 2; ++ks) {
      bf16x8 af[4], bfr[4];
#pragma unroll
      for (int mi = 0; mi < 4; ++mi) {
        const int r = wr * 64 + mi * 16 + lr;
        const int s = ks * 4 + lg;
        af[mi] = *reinterpret_cast<const bf16x8*>(&As[r * 64 + ((s ^ (r & 7)) << 3)]);
      }
#pragma unroll
      for (int ni = 0; ni < 4; ++ni) {
        const int r = wc * 64 + ni * 16 + lr;
        const int s = ks * 4 + lg;
        bfr[ni] = *reinterpret_cast<const bf16x8*>(&Bs[r * 64 + ((s ^ (r & 7)) << 3)]);
      }
#pragma unroll
      for (int mi = 0; mi < 4; ++mi)
#pragma unroll
        for (int ni = 0; ni < 4; ++ni)
          acc[mi][ni] = __builtin_amdgcn_mfma_f32_16x16x32_bf16(af[mi], bfr[ni],
                                                                acc[mi][ni], 0, 0, 0);
    }
    if (kt < 3) {
      __syncthreads();
#pragma unroll
      for (int c = 0; c < 4; ++c) {
        caf[2 * c] = naf[2 * c];
        caf[2 * c + 1] = naf[2 * c + 1];
        cb[c] = nb[c];
      }
    }
  }

#pragma unroll
  for (int mi = 0; mi < 4; ++mi) {
#pragma unroll
    for (int reg = 0; reg < 4; ++reg) {
      const int row = m0 + wr * 64 + mi * 16 + lg * 4 + reg;
      if (row < M) {
#pragma unroll
        for (int ni = 0; ni < 4; ++ni) {
          const int col = n0 + wc * 64 + ni * 16 + lr;
          outp[(long long)row * 256 + col] = f2fp8(acc[mi][ni][reg] + bias[col]);
        }
      }
    }
  }
}

// ---------------------------------------------------------------------------
// Softmax over each 16-wide group; logits live at offaw[nq*384 + 256 + t].
// ---------------------------------------------------------------------------
__global__ __launch_bounds__(128) void k_softmax16(float* __restrict__ offaw) {
  const int nq = blockIdx.x;
  const int t = threadIdx.x;
  float* p = offaw + (long long)nq * 384 + 256 + t;
  float v = *p;
  float mx = v;
#pragma unroll
  for (int s = 1; s < 16; s <<= 1) mx = fmaxf(mx, __shfl_xor(mx, s));
  const float e = expf(v - mx);
  float sm = e;
#pragma unroll
  for (int s = 1; s < 16; s <<= 1) sm += __shfl_xor(sm, s);
  *p = e / sm;
}

// ---------------------------------------------------------------------------
// Camera projection of reference points + visibility mask.
// ---------------------------------------------------------------------------
__global__ __launch_bounds__(256) void k_proj_ref(const float* __restrict__ refpts,
                                                  const float* __restrict__ l2i,
                                                  const float* __restrict__ img_shape,
                                                  float* __restrict__ refcam,
                                                  float* __restrict__ valid) {
  const int idx = blockIdx.x * blockDim.x + threadIdx.x;
  if (idx >= kCams * kNQ) return;
  const int cam = idx / kNQ;
  const int nq = idx - cam * kNQ;
  const float* Mp = l2i + cam * 12;
  float m[12];
#pragma unroll
  for (int i = 0; i < 12; ++i) m[i] = Mp[i];
  const float ih = img_shape[cam * 2 + 0];
  const float iw = img_shape[cam * 2 + 1];
  float anyv = 0.f;
  float* rcout = refcam + (long long)idx * 8;
#pragma unroll
  for (int r = 0; r < 4; ++r) {
    const float* rp = refpts + ((long long)nq * 4 + r) * 3;
    const float X = rp[0] * 102.4f + (-51.2f);
    const float Y = rp[1] * 102.4f + (-51.2f);
    const float Z = rp[2] * 8.0f + (-5.0f);
    const float cx = m[0] * X + m[1] * Y + m[2] * Z + m[3];
    const float cy = m[4] * X + m[5] * Y + m[6] * Z + m[7];
    const float cz = m[8] * X + m[9] * Y + m[10] * Z + m[11];
    const float zc = fmaxf(cz, kEps);
    const float xn = cx / zc / iw;
    const float yn = cy / zc / ih;
    rcout[r * 2 + 0] = xn;
    rcout[r * 2 + 1] = yn;
    if ((cz > kEps) && (xn > 0.f) && (xn < 1.f) && (yn > 0.f) && (yn < 1.f)) anyv = 1.f;
  }
  valid[idx] = anyv;
}

// ---------------------------------------------------------------------------
// Bilinear sampling with fused masked camera-mean; vproj is fp8-e4m3
// [cam][n][256]. One wave per query (block = 64); lane = h*8 + d4 (4 ch).
// ---------------------------------------------------------------------------
__global__ __launch_bounds__(64) void k_sample(const u8* __restrict__ vproj,
                                               const float* __restrict__ refcam,
                                               const float* __restrict__ offaw,
                                               const float* __restrict__ valid,
                                               u16* __restrict__ pre,
                                               float* __restrict__ cflag) {
  const int nq = blockIdx.x;
  const int lane = threadIdx.x;
  const int h = lane >> 3;
  const int d4 = lane & 7;

  static constexpr int SHH[4] = {64, 32, 16, 8};
  static constexpr int SHW[4] = {160, 80, 40, 20};
  static constexpr int LSI[4] = {0, 10240, 12800, 13440};

  const float* offp = offaw + (long long)nq * 384 + h * 32;
  const float* awp = offaw + (long long)nq * 384 + 256 + h * 16;

  float vl[kCams];
#pragma unroll
  for (int c = 0; c < kCams; ++c) vl[c] = valid[c * kNQ + nq];

  float4 acc4 = {0.f, 0.f, 0.f, 0.f};
  float count = 0.f;

  for (int cam = 0; cam < kCams; ++cam) {
    if (vl[cam] == 0.f) continue;  // wave-uniform skip
    count += 1.f;

    const float* rcp = refcam + (long long)(cam * kNQ + nq) * 8;
    const float4 rcA = *reinterpret_cast<const float4*>(rcp);
    const float4 rcB = *reinterpret_cast<const float4*>(rcp + 4);
    const float rx[4] = {rcA.x, rcA.z, rcB.x, rcB.z};
    const float ry[4] = {rcA.y, rcA.w, rcB.y, rcB.w};

#pragma unroll
    for (int l = 0; l < 4; ++l) {
      const int Hl = SHH[l];
      const int Wl = SHW[l];
      const float Hf = (float)Hl;
      const float Wf = (float)Wl;
      const float4 aw4 = *reinterpret_cast<const float4*>(awp + l * 4);
      const float4 ofA = *reinterpret_cast<const float4*>(offp + l * 8);
      const float4 ofB = *reinterpret_cast<const float4*>(offp + l * 8 + 4);
      const u8* vf = vproj + ((long long)(cam * kNK + LSI[l])) * 256 + h * 32 + d4 * 4;

      const float ox[4] = {ofA.x, ofA.z, ofB.x, ofB.z};
      const float oy[4] = {ofA.y, ofA.w, ofB.y, ofB.w};
      const float wr[4] = {aw4.x, aw4.y, aw4.z, aw4.w};

#pragma unroll
      for (int r = 0; r < 4; ++r) {
        const float x = fmaf(rx[r], Wf, ox[r]) - 0.5f;
        const float y = fmaf(ry[r], Hf, oy[r]) - 0.5f;
        const float x0 = floorf(x);
        const float y0 = floorf(y);
        const float lx = x - x0;
        const float ly = y - y0;
        const int ix = (int)x0;
        const int iy = (int)y0;
        const int ix0 = min(max(ix, 0), Wl - 1);
        const int ix1 = min(max(ix + 1, 0), Wl - 1);
        const int iy0 = min(max(iy, 0), Hl - 1);
        const int iy1 = min(max(iy + 1, 0), Hl - 1);
        const bool bx0 = (ix >= 0) & (ix < Wl);
        const bool bx1 = (ix >= -1) & (ix + 1 < Wl);
        const bool by0 = (iy >= 0) & (iy < Hl);
        const bool by1 = (iy >= -1) & (iy + 1 < Hl);
        const float w = wr[r];
        const float wy0 = w * (1.f - ly);
        const float wy1 = w * ly;
        const float w00 = (by0 && bx0) ? wy0 * (1.f - lx) : 0.f;
        const float w01 = (by0 && bx1) ? wy0 * lx : 0.f;
        const float w10 = (by1 && bx0) ? wy1 * (1.f - lx) : 0.f;
        const float w11 = (by1 && bx1) ? wy1 * lx : 0.f;
        const int q00 = *reinterpret_cast<const u32*>(vf + (iy0 * Wl + ix0) * 256);
        const int q01 = *reinterpret_cast<const u32*>(vf + (iy0 * Wl + ix1) * 256);
        const int q10 = *reinterpret_cast<const u32*>(vf + (iy1 * Wl + ix0) * 256);
        const int q11 = *reinterpret_cast<const u32*>(vf + (iy1 * Wl + ix1) * 256);
        const f32x2 a00 = __builtin_amdgcn_cvt_pk_f32_fp8(q00, false);
        const f32x2 b00 = __builtin_amdgcn_cvt_pk_f32_fp8(q00, true);
        const f32x2 a01 = __builtin_amdgcn_cvt_pk_f32_fp8(q01, false);
        const f32x2 b01 = __builtin_amdgcn_cvt_pk_f32_fp8(q01, true);
        const f32x2 a10 = __builtin_amdgcn_cvt_pk_f32_fp8(q10, false);
        const f32x2 b10 = __builtin_amdgcn_cvt_pk_f32_fp8(q10, true);
        const f32x2 a11 = __builtin_amdgcn_cvt_pk_f32_fp8(q11, false);
        const f32x2 b11 = __builtin_amdgcn_cvt_pk_f32_fp8(q11, true);
        acc4.x = fmaf(w00, a00[0], fmaf(w01, a01[0], fmaf(w10, a10[0], fmaf(w11, a11[0], acc4.x))));
        acc4.y = fmaf(w00, a00[1], fmaf(w01, a01[1], fmaf(w10, a10[1], fmaf(w11, a11[1], acc4.y))));
        acc4.z = fmaf(w00, b00[0], fmaf(w01, b01[0], fmaf(w10, b10[0], fmaf(w11, b11[0], acc4.z))));
        acc4.w = fmaf(w00, b00[1], fmaf(w01, b01[1], fmaf(w10, b10[1], fmaf(w11, b11[1], acc4.w))));
      }
    }
  }

  const float inv = count > 0.f ? (1.f / count) : 0.f;
  ushort4 o;
  o.x = f2b(acc4.x * inv);
  o.y = f2b(acc4.y * inv);
  o.z = f2b(acc4.z * inv);
  o.w = f2b(acc4.w * inv);
  *reinterpret_cast<ushort4*>(pre + (long long)nq * kC + h * 32 + d4 * 4) = o;
  if (lane == 0) cflag[nq] = count > 0.f ? 1.f : 0.f;
}

}  // namespace

extern "C" void kernel_launch(void* const* d_in, const int* in_sizes, int n_in,
                              void* d_out, int out_size, void* d_ws, size_t ws_size,
                              hipStream_t stream) {
  (void)in_sizes; (void)n_in; (void)out_size; (void)ws_size;
  const float* query     = (const float*)d_in[0];
  const float* query_pos = (const float*)d_in[1];
  const float* value     = (const float*)d_in[2];
  const float* refpts    = (const float*)d_in[3];
  const float* l2i       = (const float*)d_in[4];
  const float* img_shape = (const float*)d_in[5];
  const float* W_val  = (const float*)d_in[8];
  const float* b_val  = (const float*)d_in[9];
  const float* W_samp = (const float*)d_in[10];
  const float* b_samp = (const float*)d_in[11];
  const float* W_attn = (const float*)d_in[12];
  const float* b_attn = (const float*)d_in[13];
  const float* W_dout = (const float*)d_in[14];
  const float* b_dout = (const float*)d_in[15];
  const float* W_out  = (const float*)d_in[16];
  const float* b_out  = (const float*)d_in[17];

  // workspace layout (bytes, 16B-aligned)
  char* p = (char*)d_ws;
  float* offaw  = (float*)p;  p += 15360000;   // [10000][384] f32 (off | aw)
  float* refcam = (float*)p;  p += 1920000;    // [6*10000][8] f32
  float* valid  = (float*)p;  p += 240000;     // [6*10000] f32
  float* cflag  = (float*)p;  p += 40000;      // [10000] f32
  u8*    vproj  = (u8*)p;     p += 20889600;   // [6*13600][256] fp8-e4m3
  u16*   pre    = (u16*)p;    p += 5120000;    // [10000][256] bf16
  u16*   slots  = (u16*)p;    p += 5120000;    // [10000][256] bf16
  u16*   qpq    = (u16*)p;    p += 5120000;    // [10000][256] bf16
  u16*   WtVal  = (u16*)p;    p += 131072;     // [256][256] bf16
  u16*   WtSA   = (u16*)p;    p += 196608;     // [384][256] bf16 (samp|attn)
  u16*   WtDout = (u16*)p;    p += 131072;
  u16*   WtOut  = (u16*)p;    p += 131072;
  float* out    = (float*)d_out;

  // weight transposes (1 launch)
  k_cvt_w_all<<<dim3(36, 8), 256, 0, stream>>>(W_val, W_samp, W_attn, W_dout, W_out,
                                               WtVal, WtSA, WtDout, WtOut);

  // q + q_pos -> bf16
  k_cvt_add<<<dim3(1250), 256, 0, stream>>>(query, query_pos, qpq);

  // camera projection + visibility
  k_proj_ref<<<dim3((kCams * kNQ + 255) / 256), 256, 0, stream>>>(refpts, l2i,
                                                                  img_shape, refcam,
                                                                  valid);

  // combined sampling-offset + attention-logit projection -> offaw [10000][384]
  k_mfma<false, false><<<dim3(79, 3), 256, 0, stream>>>(
      qpq, WtSA, b_samp, b_attn, 256, nullptr, nullptr, offaw, kNQ, 384);
  k_softmax16<<<dim3(kNQ), 128, 0, stream>>>(offaw);

  // value projection with fused f32->bf16 staging -> vproj fp8 [cam][n][256]
  k_mfma_vproj<<<dim3(638, 2), 256, 0, stream>>>(value, WtVal, b_val, vproj);

  // bilinear sampling + fused masked camera-mean -> pre, cflag
  k_sample<<<dim3(kNQ), 64, 0, stream>>>(vproj, refcam, offaw, valid, pre, cflag);

  // dout projection on camera-averaged features (bias scaled by cflag)
  k_mfma<true, false><<<dim3(79, 2), 256, 0, stream>>>(
      pre, WtDout, b_dout, nullptr, 0, cflag, nullptr, slots, kNQ, 256);

  // final projection + residual
  k_mfma<false, true><<<dim3(79, 2), 256, 0, stream>>>(
      slots, WtOut, b_out, nullptr, 0, nullptr, query, out, kNQ, 256);
}